// Round 6
// baseline (400.504 us; speedup 1.0000x reference)
//
#include <hip/hip_runtime.h>

typedef unsigned short u16;
typedef __attribute__((ext_vector_type(8))) short bf16x8;
typedef __attribute__((ext_vector_type(8))) unsigned short u16x8;
typedef __attribute__((ext_vector_type(4))) float f32x4;

#define NPTS 65536
#define MTOT 1048576            // NPTS * NS
#define EPSb 1e-5f

// ---- workspace layout ----
// float-offsets from ws base:
#define XQ_OFF  0u              // f32 [NPTS,64]            16 MB
#define T_OFF   4194304u        // f32 [MTOT,3] raw bn1 in  12 MB
#define W1P_OFF 7340032u        // f32 [MTOT,8]             32 MB
#define ST_OFF  15728640u       // f32 [150] stats
// ushort-offsets from ws base:
#define XK_US   31457792u       // bf16 [NPTS,64]            8 MB
#define DKV_US  35652096u       // bf16 [NPTS,64] (xv-xk)    8 MB
#define W0_US   39846400u       // bf16 [MTOT,64]          128 MB

__device__ __forceinline__ float bf2f(u16 h) {
    return __uint_as_float(((unsigned)h) << 16);
}
__device__ __forceinline__ u16 f2bf(float f) {
    unsigned u = __float_as_uint(f);
    u += 0x7fffu + ((u >> 16) & 1u);      // round-to-nearest-even
    return (u16)(u >> 16);
}

// ---------------------------------------------------------------------------
// K1: xq/xk/dkv projections via MFMA ([65536,64] @ [64,192] bf16) + BN1 stats.
// dkv = (xv+bv) - (xk+bk) so K4 can rebuild xv_g + pr = w0 + xq + dkv_g.
// grid=1024 x 256: wave = 16 points.
// ---------------------------------------------------------------------------
__global__ __launch_bounds__(256) void k1_proj_bn1(
    const float* __restrict__ p, const float* __restrict__ x, const int* __restrict__ idx,
    const float* __restrict__ Wq, const float* __restrict__ bq,
    const float* __restrict__ Wk, const float* __restrict__ bk,
    const float* __restrict__ Wv, const float* __restrict__ bv,
    const float* __restrict__ Wp1, const float* __restrict__ bp1,
    float* __restrict__ ws)
{
    u16* wsu = (u16*)ws;
    __shared__ float sred[6];
    const int tid   = threadIdx.x;
    const int lane  = tid & 63;
    const int wid   = tid >> 6;
    const int col16 = lane & 15;
    const int quad  = lane >> 4;
    if (tid < 6) sred[tid] = 0.0f;
    __syncthreads();

    // ---- load B fragments: B[k=quad*8+j][n=16t+col16], bf16 ----
    const float* Wm[3] = { Wq, Wk, Wv };
    bf16x8 bf[3][4][2];
#pragma unroll
    for (int M = 0; M < 3; ++M)
#pragma unroll
        for (int t = 0; t < 4; ++t)
#pragma unroll
            for (int h = 0; h < 2; ++h) {
                bf16x8 tmp;
#pragma unroll
                for (int j = 0; j < 8; ++j)
                    tmp[j] = (short)f2bf(Wm[M][(h * 32 + quad * 8 + j) * 64 + t * 16 + col16]);
                bf[M][t][h] = tmp;
            }
    float bq_t[4], bk_t[4], bv_t[4];
#pragma unroll
    for (int t = 0; t < 4; ++t) {
        bq_t[t] = bq[t * 16 + col16];
        bk_t[t] = bk[t * 16 + col16];
        bv_t[t] = bv[t * 16 + col16];
    }

    float* xq   = ws + XQ_OFF;
    u16*  xkb   = wsu + XK_US;
    u16*  dkvb  = wsu + DKV_US;

    const int gw = blockIdx.x * 4 + wid;              // 0..4095
    {
        const int n0 = gw * 16;
        const float* xrow = x + (unsigned)(n0 + col16) * 64u;
        const float4 fa0 = *(const float4*)&xrow[quad * 8];
        const float4 fa1 = *(const float4*)&xrow[quad * 8 + 4];
        const float4 fb0 = *(const float4*)&xrow[32 + quad * 8];
        const float4 fb1 = *(const float4*)&xrow[32 + quad * 8 + 4];
        bf16x8 a0, a1;
        a0[0] = (short)f2bf(fa0.x); a0[1] = (short)f2bf(fa0.y);
        a0[2] = (short)f2bf(fa0.z); a0[3] = (short)f2bf(fa0.w);
        a0[4] = (short)f2bf(fa1.x); a0[5] = (short)f2bf(fa1.y);
        a0[6] = (short)f2bf(fa1.z); a0[7] = (short)f2bf(fa1.w);
        a1[0] = (short)f2bf(fb0.x); a1[1] = (short)f2bf(fb0.y);
        a1[2] = (short)f2bf(fb0.z); a1[3] = (short)f2bf(fb0.w);
        a1[4] = (short)f2bf(fb1.x); a1[5] = (short)f2bf(fb1.y);
        a1[6] = (short)f2bf(fb1.z); a1[7] = (short)f2bf(fb1.w);

#pragma unroll
        for (int t = 0; t < 4; ++t) {
            f32x4 aq = {0,0,0,0}, ak = {0,0,0,0}, av = {0,0,0,0};
            aq = __builtin_amdgcn_mfma_f32_16x16x32_bf16(a0, bf[0][t][0], aq, 0, 0, 0);
            aq = __builtin_amdgcn_mfma_f32_16x16x32_bf16(a1, bf[0][t][1], aq, 0, 0, 0);
            ak = __builtin_amdgcn_mfma_f32_16x16x32_bf16(a0, bf[1][t][0], ak, 0, 0, 0);
            ak = __builtin_amdgcn_mfma_f32_16x16x32_bf16(a1, bf[1][t][1], ak, 0, 0, 0);
            av = __builtin_amdgcn_mfma_f32_16x16x32_bf16(a0, bf[2][t][0], av, 0, 0, 0);
            av = __builtin_amdgcn_mfma_f32_16x16x32_bf16(a1, bf[2][t][1], av, 0, 0, 0);
#pragma unroll
            for (int r = 0; r < 4; ++r) {
                const unsigned row = (unsigned)(n0 + quad * 4 + r);
                const unsigned o   = row * 64u + (unsigned)(t * 16 + col16);
                const float qv = aq[r] + bq_t[t];
                const float kv = ak[r] + bk_t[t];
                const float vv = av[r] + bv_t[t];
                xq[o]   = qv;
                xkb[o]  = f2bf(kv);
                dkvb[o] = f2bf(vv - kv);
            }
        }
    }

    // ---- BN1 stats + store raw T: this block's 1024 pairs ----
    const int base = blockIdx.x * 64;
    const float w00 = Wp1[0], w01 = Wp1[1], w02 = Wp1[2];
    const float w10 = Wp1[3], w11 = Wp1[4], w12 = Wp1[5];
    const float w20 = Wp1[6], w21 = Wp1[7], w22 = Wp1[8];
    const float c0 = bp1[0], c1 = bp1[1], c2 = bp1[2];
    float s0 = 0, s1 = 0, s2 = 0, q0 = 0, q1 = 0, q2 = 0;
#pragma unroll
    for (int m = 0; m < 4; ++m) {
        const int pl = tid + m * 256;            // 0..1023
        const int n  = base + (pl >> 4);
        const unsigned gpair = (unsigned)(base * 16 + pl);
        const int nb = idx[gpair];
        const float r0 = p[nb * 3 + 0] - p[n * 3 + 0];
        const float r1 = p[nb * 3 + 1] - p[n * 3 + 1];
        const float r2 = p[nb * 3 + 2] - p[n * 3 + 2];
        const float t0 = c0 + r0 * w00 + r1 * w10 + r2 * w20;
        const float t1 = c1 + r0 * w01 + r1 * w11 + r2 * w21;
        const float t2 = c2 + r0 * w02 + r1 * w12 + r2 * w22;
        ws[T_OFF + gpair * 3u + 0u] = t0;
        ws[T_OFF + gpair * 3u + 1u] = t1;
        ws[T_OFF + gpair * 3u + 2u] = t2;
        s0 += t0; s1 += t1; s2 += t2;
        q0 += t0 * t0; q1 += t1 * t1; q2 += t2 * t2;
    }
    atomicAdd(&sred[0], s0); atomicAdd(&sred[1], s1); atomicAdd(&sred[2], s2);
    atomicAdd(&sred[3], q0); atomicAdd(&sred[4], q1); atomicAdd(&sred[5], q2);
    __syncthreads();
    if (tid < 6) atomicAdd(&ws[ST_OFF + tid], sred[tid]);
}

// ---------------------------------------------------------------------------
// K2: w0 = xk[idx] - xq + pr ; store w0 bf16 ; BN2 stats.
// Wave-uniform scalar loads for idx/T rows (no shuffles, no DS ops).
// grid=2048 x 256: wave = 8 points; 32 waves/CU.
// ---------------------------------------------------------------------------
__global__ __launch_bounds__(256) void k2_bn2(
    const int* __restrict__ idx,
    const float* __restrict__ gp, const float* __restrict__ bp_bn,
    const float* __restrict__ Wp2, const float* __restrict__ bp2,
    float* __restrict__ ws)
{
    u16* wsu = (u16*)ws;
    __shared__ float ss[64], sq[64];
    const int tid = threadIdx.x;
    const int lane = tid & 63;
    const int gw = blockIdx.x * 4 + (tid >> 6);       // 0..8191
    if (tid < 64) { ss[tid] = 0.0f; sq[tid] = 0.0f; }

    const float invM = 1.0f / (float)MTOT;
    float A1[3], B1[3];
#pragma unroll
    for (int a = 0; a < 3; ++a) {
        const float mean = ws[ST_OFF + a] * invM;
        const float var  = ws[ST_OFF + 3 + a] * invM - mean * mean;
        const float sc = gp[a] * rsqrtf(var + EPSb);
        A1[a] = sc; B1[a] = bp_bn[a] - mean * sc;
    }
    const float wp20 = Wp2[lane], wp21 = Wp2[64 + lane], wp22 = Wp2[128 + lane];
    const float bp2c = bp2[lane];
    const float* xq  = ws + XQ_OFF;
    const float* T   = ws + T_OFF;
    const u16*  xkb  = wsu + XK_US;
    u16*        w0b  = wsu + W0_US;

    float s = 0.0f, q = 0.0f;
    const int n0 = gw * 8;

    for (int nn = 0; nn < 8; ++nn) {
        const int n  = n0 + nn;
        const int nu = __builtin_amdgcn_readfirstlane(n);

        // wave-uniform idx row (s_load_dwordx4 x4)
        const int4* ir4 = (const int4*)(idx + (unsigned)nu * 16u);
        const int4 i0 = ir4[0], i1 = ir4[1], i2 = ir4[2], i3 = ir4[3];
        const int nbs[16] = { i0.x, i0.y, i0.z, i0.w, i1.x, i1.y, i1.z, i1.w,
                              i2.x, i2.y, i2.z, i2.w, i3.x, i3.y, i3.z, i3.w };
        // issue the 16 row-gathers early
        u16 kr[16];
#pragma unroll
        for (int j = 0; j < 16; ++j) kr[j] = xkb[(unsigned)nbs[j] * 64u + lane];

        // wave-uniform T row (48 floats) + per-lane xq
        float tr[48];
        const float4* Tr4 = (const float4*)(T + (unsigned)nu * 48u);
#pragma unroll
        for (int c = 0; c < 12; ++c) {
            const float4 v = Tr4[c];
            tr[4 * c + 0] = v.x; tr[4 * c + 1] = v.y;
            tr[4 * c + 2] = v.z; tr[4 * c + 3] = v.w;
        }
        const float xqc  = xq[(unsigned)nu * 64u + lane];
        const float base = bp2c - xqc;

        u16* wrow = w0b + (unsigned)(n * 16) * 64u + lane;
#pragma unroll
        for (int j = 0; j < 16; ++j) {
            const float t0 = fmaxf(fmaf(tr[3 * j + 0], A1[0], B1[0]), 0.0f);
            const float t1 = fmaxf(fmaf(tr[3 * j + 1], A1[1], B1[1]), 0.0f);
            const float t2 = fmaxf(fmaf(tr[3 * j + 2], A1[2], B1[2]), 0.0f);
            const float prx = base + t0 * wp20 + t1 * wp21 + t2 * wp22;
            const float w0 = bf2f(kr[j]) + prx;
            s += w0; q = fmaf(w0, w0, q);
            wrow[j * 64] = f2bf(w0);
        }
    }
    __syncthreads();
    atomicAdd(&ss[lane], s); atomicAdd(&sq[lane], q);
    __syncthreads();
    if (tid < 64) {
        atomicAdd(&ws[ST_OFF + 6 + tid], ss[tid]);
        atomicAdd(&ws[ST_OFF + 70 + tid], sq[tid]);
    }
}

// ---------------------------------------------------------------------------
// K3: w1' = relu(bn2(w0)) @ Ww1 + bw1 via MFMA, barrier-free, no LDS staging.
// grid=2048 x 256: wave = 8 tiles of 16 pairs; 32 waves/CU.
// ---------------------------------------------------------------------------
__global__ __launch_bounds__(256) void k3_w1_bn3(
    const float* __restrict__ gw1, const float* __restrict__ bw1_bn,
    const float* __restrict__ Ww1, const float* __restrict__ bw1,
    float* __restrict__ ws)
{
    u16* wsu = (u16*)ws;
    __shared__ float s3r[8], q3r[8];
    const int tid   = threadIdx.x;
    const int lane  = tid & 63;
    const int wid   = tid >> 6;
    const int col16 = lane & 15;
    const int quad  = lane >> 4;
    if (tid < 8) { s3r[tid] = 0.0f; q3r[tid] = 0.0f; }
    __syncthreads();

    const float invM = 1.0f / (float)MTOT;
    float A2q[8], B2q[8], A2h[8], B2h[8];
#pragma unroll
    for (int j = 0; j < 8; ++j) {
        {
            const int c = quad * 8 + j;
            const float mean = ws[ST_OFF + 6 + c] * invM;
            const float var  = ws[ST_OFF + 70 + c] * invM - mean * mean;
            A2q[j] = gw1[c] * rsqrtf(var + EPSb);
            B2q[j] = bw1_bn[c] - mean * A2q[j];
        }
        {
            const int c = 32 + quad * 8 + j;
            const float mean = ws[ST_OFF + 6 + c] * invM;
            const float var  = ws[ST_OFF + 70 + c] * invM - mean * mean;
            A2h[j] = gw1[c] * rsqrtf(var + EPSb);
            B2h[j] = bw1_bn[c] - mean * A2h[j];
        }
    }
    bf16x8 b0, b1;
#pragma unroll
    for (int j = 0; j < 8; ++j) {
        const int k0 = quad * 8 + j;
        b0[j] = (col16 < 8) ? (short)f2bf(Ww1[k0 * 8 + col16]) : (short)0;
        b1[j] = (col16 < 8) ? (short)f2bf(Ww1[(k0 + 32) * 8 + col16]) : (short)0;
    }
    const float bw1c = (col16 < 8) ? bw1[col16] : 0.0f;

    const u16* w0b = wsu + W0_US;
    float* w1p = ws + W1P_OFF;
    const int wgid = blockIdx.x * 4 + wid;            // 0..8191
    float bs = 0.0f, bq2 = 0.0f;

#pragma unroll 2
    for (int t = 0; t < 8; ++t) {
        const int pair0 = (wgid * 8 + t) * 16;
        const u16* rowp = w0b + (unsigned)(pair0 + col16) * 64u;
        const u16x8 r0 = *(const u16x8*)(rowp + quad * 8);
        const u16x8 r1 = *(const u16x8*)(rowp + 32 + quad * 8);
        bf16x8 a0, a1;
#pragma unroll
        for (int j = 0; j < 8; ++j) {
            float f0 = fmaxf(fmaf(bf2f(r0[j]), A2q[j], B2q[j]), 0.0f);
            float f1 = fmaxf(fmaf(bf2f(r1[j]), A2h[j], B2h[j]), 0.0f);
            a0[j] = (short)f2bf(f0);
            a1[j] = (short)f2bf(f1);
        }
        f32x4 acc = {0.0f, 0.0f, 0.0f, 0.0f};
        acc = __builtin_amdgcn_mfma_f32_16x16x32_bf16(a0, b0, acc, 0, 0, 0);
        acc = __builtin_amdgcn_mfma_f32_16x16x32_bf16(a1, b1, acc, 0, 0, 0);
        if (col16 < 8) {
#pragma unroll
            for (int r = 0; r < 4; ++r) {
                const float o = acc[r] + bw1c;
                w1p[(unsigned)(pair0 + quad * 4 + r) * 8u + (unsigned)col16] = o;
                bs += o;
                bq2 = fmaf(o, o, bq2);
            }
        }
    }
    if (col16 < 8) {
        atomicAdd(&s3r[col16], bs);
        atomicAdd(&q3r[col16], bq2);
    }
    __syncthreads();
    if (tid < 8) {
        atomicAdd(&ws[ST_OFF + 134 + tid], s3r[tid]);
        atomicAdd(&ws[ST_OFF + 142 + tid], q3r[tid]);
    }
}

// ---------------------------------------------------------------------------
// K4: bn3 -> relu -> @Ww2 -> softmax -> aggregate using u = w0 + xq + dkv_g.
// Wave-private LDS (no barriers); wave-uniform scalar idx loads.
// grid=2048 x 256: wave = 8 points; 32 waves/CU.
// ---------------------------------------------------------------------------
__global__ __launch_bounds__(256) void k4_final(
    const int* __restrict__ idx,
    const float* __restrict__ gw2, const float* __restrict__ bw2_bn,
    const float* __restrict__ Ww2, const float* __restrict__ bw2,
    const float* __restrict__ ws, float* __restrict__ out)
{
    const u16* wsu = (const u16*)ws;
    __shared__ float sv3[4][16][8];
    __shared__ float sw2[4][16][8];
    const int tid = threadIdx.x;
    const int lane = tid & 63;
    const int wid = tid >> 6;
    const int gw = blockIdx.x * 4 + wid;              // 0..8191
    const int tt = lane & 7;
    const int j1 = lane >> 3;

    const float invM = 1.0f / (float)MTOT;
    const float mean3 = ws[ST_OFF + 134 + tt] * invM;
    const float var3  = ws[ST_OFF + 142 + tt] * invM - mean3 * mean3;
    const float A3 = gw2[tt] * rsqrtf(var3 + EPSb);
    const float B3 = bw2_bn[tt] - mean3 * A3;
    float ww2c[8];
#pragma unroll
    for (int u = 0; u < 8; ++u) ww2c[u] = Ww2[u * 8 + tt];
    const float bw2c = bw2[tt];

    const float* xq  = ws + XQ_OFF;
    const float* w1p = ws + W1P_OFF;
    const u16*  dkvb = wsu + DKV_US;
    const u16*  w0b  = wsu + W0_US;

    const int n0 = gw * 8;
    for (int it = 0; it < 8; ++it) {
        const int n  = n0 + it;
        const int nu = __builtin_amdgcn_readfirstlane(n);

        // wave-uniform idx row
        const int4* ir4 = (const int4*)(idx + (unsigned)nu * 16u);
        const int4 i0 = ir4[0], i1 = ir4[1], i2 = ir4[2], i3 = ir4[3];
        const int nbs[16] = { i0.x, i0.y, i0.z, i0.w, i1.x, i1.y, i1.z, i1.w,
                              i2.x, i2.y, i2.z, i2.w, i3.x, i3.y, i3.z, i3.w };
        // issue gathers + streaming loads early
        u16 dk[16];
#pragma unroll
        for (int j = 0; j < 16; ++j) dk[j] = dkvb[(unsigned)nbs[j] * 64u + lane];
        u16 w0r[16];
#pragma unroll
        for (int j = 0; j < 16; ++j) w0r[j] = w0b[(unsigned)(n * 16 + j) * 64u + lane];
        const float v1  = w1p[(unsigned)nu * 128u + lane];
        const float v2  = w1p[(unsigned)nu * 128u + 64u + lane];
        const float xqc = xq[(unsigned)nu * 64u + lane];

        // bn3 -> relu -> 8x8 matmul (wave-private LDS, compiler lgkmcnt orders)
        sv3[wid][j1][tt]     = fmaxf(fmaf(v1, A3, B3), 0.0f);
        sv3[wid][j1 + 8][tt] = fmaxf(fmaf(v2, A3, B3), 0.0f);
        {
            float a0 = bw2c, a1 = bw2c;
#pragma unroll
            for (int u = 0; u < 8; ++u) {
                a0 = fmaf(sv3[wid][j1][u], ww2c[u], a0);
                a1 = fmaf(sv3[wid][j1 + 8][u], ww2c[u], a1);
            }
            sw2[wid][j1][tt]     = a0;
            sw2[wid][j1 + 8][tt] = a1;
        }
        // softmax over 16 neighbors
        float mx = -1e30f;
#pragma unroll
        for (int j = 0; j < 16; ++j) mx = fmaxf(mx, sw2[wid][j][tt]);
        float e[16];
        float sum = 0.0f;
#pragma unroll
        for (int j = 0; j < 16; ++j) { e[j] = __expf(sw2[wid][j][tt] - mx); sum += e[j]; }

        // aggregate: u = w0 + xq + dkv
        float acc = 0.0f;
#pragma unroll
        for (int j = 0; j < 16; ++j) {
            const float uu = (bf2f(w0r[j]) + xqc) + bf2f(dk[j]);
            acc = fmaf(uu, e[j], acc);
        }
        out[(unsigned)n * 64u + lane] = acc * (1.0f / sum);
    }
}

extern "C" void kernel_launch(void* const* d_in, const int* in_sizes, int n_in,
                              void* d_out, int out_size, void* d_ws, size_t ws_size,
                              hipStream_t stream)
{
    const float* p      = (const float*)d_in[0];
    const float* x      = (const float*)d_in[1];
    const int*   idx    = (const int*)d_in[2];
    const float* Wq     = (const float*)d_in[3];
    const float* bq     = (const float*)d_in[4];
    const float* Wk     = (const float*)d_in[5];
    const float* bk     = (const float*)d_in[6];
    const float* Wv     = (const float*)d_in[7];
    const float* bv     = (const float*)d_in[8];
    const float* Wp1    = (const float*)d_in[9];
    const float* bp1    = (const float*)d_in[10];
    const float* gp     = (const float*)d_in[11];
    const float* bp_bn  = (const float*)d_in[12];
    const float* Wp2    = (const float*)d_in[13];
    const float* bp2    = (const float*)d_in[14];
    const float* gw1    = (const float*)d_in[15];
    const float* bw1_bn = (const float*)d_in[16];
    const float* Ww1    = (const float*)d_in[17];
    const float* bw1    = (const float*)d_in[18];
    const float* gw2    = (const float*)d_in[19];
    const float* bw2_bn = (const float*)d_in[20];
    const float* Ww2    = (const float*)d_in[21];
    const float* bw2    = (const float*)d_in[22];
    float* ws  = (float*)d_ws;
    float* out = (float*)d_out;
    (void)in_sizes; (void)n_in; (void)out_size; (void)ws_size;

    hipMemsetAsync((char*)d_ws + (size_t)ST_OFF * 4, 0, 150 * sizeof(float), stream);

    k1_proj_bn1<<<1024, 256, 0, stream>>>(p, x, idx, Wq, bq, Wk, bk, Wv, bv, Wp1, bp1, ws);
    k2_bn2<<<2048, 256, 0, stream>>>(idx, gp, bp_bn, Wp2, bp2, ws);
    k3_w1_bn3<<<2048, 256, 0, stream>>>(gw1, bw1_bn, Ww1, bw1, ws);
    k4_final<<<2048, 256, 0, stream>>>(idx, gw2, bw2_bn, Ww2, bw2, ws, out);
}

// Round 7
// 317.209 us; speedup vs baseline: 1.2626x; 1.2626x over previous
//
#include <hip/hip_runtime.h>

typedef unsigned short u16;
typedef __attribute__((ext_vector_type(8))) short bf16x8;
typedef __attribute__((ext_vector_type(8))) unsigned short u16x8;
typedef __attribute__((ext_vector_type(4))) float f32x4;

#define NPTS 65536
#define MTOT 1048576            // NPTS * NS
#define EPSb 1e-5f

// ---- workspace layout ----
// float-offsets from ws base:
#define XQ_OFF  0u              // f32 [NPTS,64]            16 MB
#define T_OFF   4194304u        // f32 [MTOT,3] raw bn1 in  12 MB
#define W1P_OFF 7340032u        // f32 [MTOT,8]             32 MB
#define ST_OFF  15728640u       // f32 [150] stats
// ushort-offsets from ws base:
#define XK_US   31457792u       // bf16 [NPTS,64]            8 MB
#define DKV_US  35652096u       // bf16 [NPTS,64] (xv-xk)    8 MB
#define W0_US   39846400u       // bf16 [MTOT,64]          128 MB

__device__ __forceinline__ float bf2f(u16 h) {
    return __uint_as_float(((unsigned)h) << 16);
}
__device__ __forceinline__ u16 f2bf(float f) {
    unsigned u = __float_as_uint(f);
    u += 0x7fffu + ((u >> 16) & 1u);      // round-to-nearest-even
    return (u16)(u >> 16);
}

// ---------------------------------------------------------------------------
// K1: xq/xk/dkv projections via MFMA ([65536,64] @ [64,192] bf16) + BN1 stats.
// dkv = (xv+bv) - (xk+bk) so K4 can rebuild xv_g + pr = w0 + xq + dkv_g.
// grid=512 x 256: wave = 2 groups of 16 points (round-5 grid — 2048-block
// regrid regressed; see R6 post-mortem).
// ---------------------------------------------------------------------------
__global__ __launch_bounds__(256) void k1_proj_bn1(
    const float* __restrict__ p, const float* __restrict__ x, const int* __restrict__ idx,
    const float* __restrict__ Wq, const float* __restrict__ bq,
    const float* __restrict__ Wk, const float* __restrict__ bk,
    const float* __restrict__ Wv, const float* __restrict__ bv,
    const float* __restrict__ Wp1, const float* __restrict__ bp1,
    float* __restrict__ ws)
{
    u16* wsu = (u16*)ws;
    __shared__ float sred[6];
    const int tid   = threadIdx.x;
    const int lane  = tid & 63;
    const int wid   = tid >> 6;
    const int col16 = lane & 15;
    const int quad  = lane >> 4;
    if (tid < 6) sred[tid] = 0.0f;
    __syncthreads();

    // ---- load B fragments: B[k=quad*8+j][n=16t+col16], bf16 ----
    const float* Wm[3] = { Wq, Wk, Wv };
    bf16x8 bf[3][4][2];
#pragma unroll
    for (int M = 0; M < 3; ++M)
#pragma unroll
        for (int t = 0; t < 4; ++t)
#pragma unroll
            for (int h = 0; h < 2; ++h) {
                bf16x8 tmp;
#pragma unroll
                for (int j = 0; j < 8; ++j)
                    tmp[j] = (short)f2bf(Wm[M][(h * 32 + quad * 8 + j) * 64 + t * 16 + col16]);
                bf[M][t][h] = tmp;
            }
    float bq_t[4], bk_t[4], bv_t[4];
#pragma unroll
    for (int t = 0; t < 4; ++t) {
        bq_t[t] = bq[t * 16 + col16];
        bk_t[t] = bk[t * 16 + col16];
        bv_t[t] = bv[t * 16 + col16];
    }

    float* xq   = ws + XQ_OFF;
    u16*  xkb   = wsu + XK_US;
    u16*  dkvb  = wsu + DKV_US;

    const int gw = blockIdx.x * 4 + wid;              // 0..2047
#pragma unroll
    for (int g = 0; g < 2; ++g) {
        const int n0 = (gw * 2 + g) * 16;
        const float* xrow = x + (unsigned)(n0 + col16) * 64u;
        const float4 fa0 = *(const float4*)&xrow[quad * 8];
        const float4 fa1 = *(const float4*)&xrow[quad * 8 + 4];
        const float4 fb0 = *(const float4*)&xrow[32 + quad * 8];
        const float4 fb1 = *(const float4*)&xrow[32 + quad * 8 + 4];
        bf16x8 a0, a1;
        a0[0] = (short)f2bf(fa0.x); a0[1] = (short)f2bf(fa0.y);
        a0[2] = (short)f2bf(fa0.z); a0[3] = (short)f2bf(fa0.w);
        a0[4] = (short)f2bf(fa1.x); a0[5] = (short)f2bf(fa1.y);
        a0[6] = (short)f2bf(fa1.z); a0[7] = (short)f2bf(fa1.w);
        a1[0] = (short)f2bf(fb0.x); a1[1] = (short)f2bf(fb0.y);
        a1[2] = (short)f2bf(fb0.z); a1[3] = (short)f2bf(fb0.w);
        a1[4] = (short)f2bf(fb1.x); a1[5] = (short)f2bf(fb1.y);
        a1[6] = (short)f2bf(fb1.z); a1[7] = (short)f2bf(fb1.w);

#pragma unroll
        for (int t = 0; t < 4; ++t) {
            f32x4 aq = {0,0,0,0}, ak = {0,0,0,0}, av = {0,0,0,0};
            aq = __builtin_amdgcn_mfma_f32_16x16x32_bf16(a0, bf[0][t][0], aq, 0, 0, 0);
            aq = __builtin_amdgcn_mfma_f32_16x16x32_bf16(a1, bf[0][t][1], aq, 0, 0, 0);
            ak = __builtin_amdgcn_mfma_f32_16x16x32_bf16(a0, bf[1][t][0], ak, 0, 0, 0);
            ak = __builtin_amdgcn_mfma_f32_16x16x32_bf16(a1, bf[1][t][1], ak, 0, 0, 0);
            av = __builtin_amdgcn_mfma_f32_16x16x32_bf16(a0, bf[2][t][0], av, 0, 0, 0);
            av = __builtin_amdgcn_mfma_f32_16x16x32_bf16(a1, bf[2][t][1], av, 0, 0, 0);
#pragma unroll
            for (int r = 0; r < 4; ++r) {
                const unsigned row = (unsigned)(n0 + quad * 4 + r);
                const unsigned o   = row * 64u + (unsigned)(t * 16 + col16);
                const float qv = aq[r] + bq_t[t];
                const float kv = ak[r] + bk_t[t];
                const float vv = av[r] + bv_t[t];
                xq[o]   = qv;
                xkb[o]  = f2bf(kv);
                dkvb[o] = f2bf(vv - kv);
            }
        }
    }

    // ---- BN1 stats + store raw T: this block's 2048 pairs ----
    const int base = blockIdx.x * 128;
    const float w00 = Wp1[0], w01 = Wp1[1], w02 = Wp1[2];
    const float w10 = Wp1[3], w11 = Wp1[4], w12 = Wp1[5];
    const float w20 = Wp1[6], w21 = Wp1[7], w22 = Wp1[8];
    const float c0 = bp1[0], c1 = bp1[1], c2 = bp1[2];
    float s0 = 0, s1 = 0, s2 = 0, q0 = 0, q1 = 0, q2 = 0;
#pragma unroll
    for (int m = 0; m < 8; ++m) {
        const int pl = tid + m * 256;            // 0..2047
        const int n  = base + (pl >> 4);
        const unsigned gpair = (unsigned)(base * 16 + pl);
        const int nb = idx[gpair];
        const float r0 = p[nb * 3 + 0] - p[n * 3 + 0];
        const float r1 = p[nb * 3 + 1] - p[n * 3 + 1];
        const float r2 = p[nb * 3 + 2] - p[n * 3 + 2];
        const float t0 = c0 + r0 * w00 + r1 * w10 + r2 * w20;
        const float t1 = c1 + r0 * w01 + r1 * w11 + r2 * w21;
        const float t2 = c2 + r0 * w02 + r1 * w12 + r2 * w22;
        ws[T_OFF + gpair * 3u + 0u] = t0;
        ws[T_OFF + gpair * 3u + 1u] = t1;
        ws[T_OFF + gpair * 3u + 2u] = t2;
        s0 += t0; s1 += t1; s2 += t2;
        q0 += t0 * t0; q1 += t1 * t1; q2 += t2 * t2;
    }
    atomicAdd(&sred[0], s0); atomicAdd(&sred[1], s1); atomicAdd(&sred[2], s2);
    atomicAdd(&sred[3], q0); atomicAdd(&sred[4], q1); atomicAdd(&sred[5], q2);
    __syncthreads();
    if (tid < 6) atomicAdd(&ws[ST_OFF + tid], sred[tid]);
}

// ---------------------------------------------------------------------------
// K2: w0 = xk[idx] - xq + pr ; store w0 bf16 ; BN2 stats.
// Wave-uniform scalar loads for idx/T rows (no DS ops). Round-5 grid:
// 1024 x 256, wave = 16 points.
// ---------------------------------------------------------------------------
__global__ __launch_bounds__(256) void k2_bn2(
    const int* __restrict__ idx,
    const float* __restrict__ gp, const float* __restrict__ bp_bn,
    const float* __restrict__ Wp2, const float* __restrict__ bp2,
    float* __restrict__ ws)
{
    u16* wsu = (u16*)ws;
    __shared__ float ss[64], sq[64];
    const int tid = threadIdx.x;
    const int lane = tid & 63;
    const int gw = blockIdx.x * 4 + (tid >> 6);       // 0..4095
    if (tid < 64) { ss[tid] = 0.0f; sq[tid] = 0.0f; }

    const float invM = 1.0f / (float)MTOT;
    float A1[3], B1[3];
#pragma unroll
    for (int a = 0; a < 3; ++a) {
        const float mean = ws[ST_OFF + a] * invM;
        const float var  = ws[ST_OFF + 3 + a] * invM - mean * mean;
        const float sc = gp[a] * rsqrtf(var + EPSb);
        A1[a] = sc; B1[a] = bp_bn[a] - mean * sc;
    }
    const float wp20 = Wp2[lane], wp21 = Wp2[64 + lane], wp22 = Wp2[128 + lane];
    const float bp2c = bp2[lane];
    const float* xq  = ws + XQ_OFF;
    const float* T   = ws + T_OFF;
    const u16*  xkb  = wsu + XK_US;
    u16*        w0b  = wsu + W0_US;

    float s = 0.0f, q = 0.0f;
    const int n0 = gw * 16;

    for (int nn = 0; nn < 16; ++nn) {
        const int n  = n0 + nn;
        const int nu = __builtin_amdgcn_readfirstlane(n);

        // wave-uniform idx row (scalar loads)
        const int4* ir4 = (const int4*)(idx + (unsigned)nu * 16u);
        const int4 i0 = ir4[0], i1 = ir4[1], i2 = ir4[2], i3 = ir4[3];
        const int nbs[16] = { i0.x, i0.y, i0.z, i0.w, i1.x, i1.y, i1.z, i1.w,
                              i2.x, i2.y, i2.z, i2.w, i3.x, i3.y, i3.z, i3.w };
        // issue the 16 row-gathers early
        u16 kr[16];
#pragma unroll
        for (int j = 0; j < 16; ++j) kr[j] = xkb[(unsigned)nbs[j] * 64u + lane];

        // wave-uniform T row (48 floats) + per-lane xq
        float tr[48];
        const float4* Tr4 = (const float4*)(T + (unsigned)nu * 48u);
#pragma unroll
        for (int c = 0; c < 12; ++c) {
            const float4 v = Tr4[c];
            tr[4 * c + 0] = v.x; tr[4 * c + 1] = v.y;
            tr[4 * c + 2] = v.z; tr[4 * c + 3] = v.w;
        }
        const float xqc  = xq[(unsigned)nu * 64u + lane];
        const float base = bp2c - xqc;

        u16* wrow = w0b + (unsigned)(n * 16) * 64u + lane;
#pragma unroll
        for (int j = 0; j < 16; ++j) {
            const float t0 = fmaxf(fmaf(tr[3 * j + 0], A1[0], B1[0]), 0.0f);
            const float t1 = fmaxf(fmaf(tr[3 * j + 1], A1[1], B1[1]), 0.0f);
            const float t2 = fmaxf(fmaf(tr[3 * j + 2], A1[2], B1[2]), 0.0f);
            const float prx = base + t0 * wp20 + t1 * wp21 + t2 * wp22;
            const float w0 = bf2f(kr[j]) + prx;
            s += w0; q = fmaf(w0, w0, q);
            wrow[j * 64] = f2bf(w0);
        }
    }
    __syncthreads();
    atomicAdd(&ss[lane], s); atomicAdd(&sq[lane], q);
    __syncthreads();
    if (tid < 64) {
        atomicAdd(&ws[ST_OFF + 6 + tid], ss[tid]);
        atomicAdd(&ws[ST_OFF + 70 + tid], sq[tid]);
    }
}

// ---------------------------------------------------------------------------
// K3: w1' = relu(bn2(w0)) @ Ww1 + bw1 via MFMA, barrier-free, no LDS staging.
// Round-5 grid: 1024 x 256, wave = 16 tiles of 16 pairs (2048-block regrid
// regressed 65 -> 117 us; see R6 post-mortem).
// ---------------------------------------------------------------------------
__global__ __launch_bounds__(256) void k3_w1_bn3(
    const float* __restrict__ gw1, const float* __restrict__ bw1_bn,
    const float* __restrict__ Ww1, const float* __restrict__ bw1,
    float* __restrict__ ws)
{
    u16* wsu = (u16*)ws;
    __shared__ float s3r[8], q3r[8];
    const int tid   = threadIdx.x;
    const int lane  = tid & 63;
    const int wid   = tid >> 6;
    const int col16 = lane & 15;
    const int quad  = lane >> 4;
    if (tid < 8) { s3r[tid] = 0.0f; q3r[tid] = 0.0f; }
    __syncthreads();

    const float invM = 1.0f / (float)MTOT;
    float A2q[8], B2q[8], A2h[8], B2h[8];
#pragma unroll
    for (int j = 0; j < 8; ++j) {
        {
            const int c = quad * 8 + j;
            const float mean = ws[ST_OFF + 6 + c] * invM;
            const float var  = ws[ST_OFF + 70 + c] * invM - mean * mean;
            A2q[j] = gw1[c] * rsqrtf(var + EPSb);
            B2q[j] = bw1_bn[c] - mean * A2q[j];
        }
        {
            const int c = 32 + quad * 8 + j;
            const float mean = ws[ST_OFF + 6 + c] * invM;
            const float var  = ws[ST_OFF + 70 + c] * invM - mean * mean;
            A2h[j] = gw1[c] * rsqrtf(var + EPSb);
            B2h[j] = bw1_bn[c] - mean * A2h[j];
        }
    }
    bf16x8 b0, b1;
#pragma unroll
    for (int j = 0; j < 8; ++j) {
        const int k0 = quad * 8 + j;
        b0[j] = (col16 < 8) ? (short)f2bf(Ww1[k0 * 8 + col16]) : (short)0;
        b1[j] = (col16 < 8) ? (short)f2bf(Ww1[(k0 + 32) * 8 + col16]) : (short)0;
    }
    const float bw1c = (col16 < 8) ? bw1[col16] : 0.0f;

    const u16* w0b = wsu + W0_US;
    float* w1p = ws + W1P_OFF;
    const int wgid = blockIdx.x * 4 + wid;            // 0..4095
    float bs = 0.0f, bq2 = 0.0f;

#pragma unroll 2
    for (int t = 0; t < 16; ++t) {
        const int pair0 = (wgid * 16 + t) * 16;
        const u16* rowp = w0b + (unsigned)(pair0 + col16) * 64u;
        const u16x8 r0 = *(const u16x8*)(rowp + quad * 8);
        const u16x8 r1 = *(const u16x8*)(rowp + 32 + quad * 8);
        bf16x8 a0, a1;
#pragma unroll
        for (int j = 0; j < 8; ++j) {
            float f0 = fmaxf(fmaf(bf2f(r0[j]), A2q[j], B2q[j]), 0.0f);
            float f1 = fmaxf(fmaf(bf2f(r1[j]), A2h[j], B2h[j]), 0.0f);
            a0[j] = (short)f2bf(f0);
            a1[j] = (short)f2bf(f1);
        }
        f32x4 acc = {0.0f, 0.0f, 0.0f, 0.0f};
        acc = __builtin_amdgcn_mfma_f32_16x16x32_bf16(a0, b0, acc, 0, 0, 0);
        acc = __builtin_amdgcn_mfma_f32_16x16x32_bf16(a1, b1, acc, 0, 0, 0);
        if (col16 < 8) {
#pragma unroll
            for (int r = 0; r < 4; ++r) {
                const float o = acc[r] + bw1c;
                w1p[(unsigned)(pair0 + quad * 4 + r) * 8u + (unsigned)col16] = o;
                bs += o;
                bq2 = fmaf(o, o, bq2);
            }
        }
    }
    if (col16 < 8) {
        atomicAdd(&s3r[col16], bs);
        atomicAdd(&q3r[col16], bq2);
    }
    __syncthreads();
    if (tid < 8) {
        atomicAdd(&ws[ST_OFF + 134 + tid], s3r[tid]);
        atomicAdd(&ws[ST_OFF + 142 + tid], q3r[tid]);
    }
}

// ---------------------------------------------------------------------------
// K4: bn3 -> relu -> @Ww2 -> softmax -> aggregate using u = w0 + xq + dkv_g.
// Wave-private LDS (no barriers); wave-uniform scalar idx loads.
// Round-5 grid: 1024 x 256, wave = 16 points.
// ---------------------------------------------------------------------------
__global__ __launch_bounds__(256) void k4_final(
    const int* __restrict__ idx,
    const float* __restrict__ gw2, const float* __restrict__ bw2_bn,
    const float* __restrict__ Ww2, const float* __restrict__ bw2,
    const float* __restrict__ ws, float* __restrict__ out)
{
    const u16* wsu = (const u16*)ws;
    __shared__ float sv3[4][16][8];
    __shared__ float sw2[4][16][8];
    const int tid = threadIdx.x;
    const int lane = tid & 63;
    const int wid = tid >> 6;
    const int gw = blockIdx.x * 4 + wid;              // 0..4095
    const int tt = lane & 7;
    const int j1 = lane >> 3;

    const float invM = 1.0f / (float)MTOT;
    const float mean3 = ws[ST_OFF + 134 + tt] * invM;
    const float var3  = ws[ST_OFF + 142 + tt] * invM - mean3 * mean3;
    const float A3 = gw2[tt] * rsqrtf(var3 + EPSb);
    const float B3 = bw2_bn[tt] - mean3 * A3;
    float ww2c[8];
#pragma unroll
    for (int u = 0; u < 8; ++u) ww2c[u] = Ww2[u * 8 + tt];
    const float bw2c = bw2[tt];

    const float* xq  = ws + XQ_OFF;
    const float* w1p = ws + W1P_OFF;
    const u16*  dkvb = wsu + DKV_US;
    const u16*  w0b  = wsu + W0_US;

    const int n0 = gw * 16;
    for (int it = 0; it < 16; ++it) {
        const int n  = n0 + it;
        const int nu = __builtin_amdgcn_readfirstlane(n);

        // wave-uniform idx row (scalar loads)
        const int4* ir4 = (const int4*)(idx + (unsigned)nu * 16u);
        const int4 i0 = ir4[0], i1 = ir4[1], i2 = ir4[2], i3 = ir4[3];
        const int nbs[16] = { i0.x, i0.y, i0.z, i0.w, i1.x, i1.y, i1.z, i1.w,
                              i2.x, i2.y, i2.z, i2.w, i3.x, i3.y, i3.z, i3.w };
        // issue gathers + streaming loads early
        u16 dk[16];
#pragma unroll
        for (int j = 0; j < 16; ++j) dk[j] = dkvb[(unsigned)nbs[j] * 64u + lane];
        u16 w0r[16];
#pragma unroll
        for (int j = 0; j < 16; ++j) w0r[j] = w0b[(unsigned)(n * 16 + j) * 64u + lane];
        const float v1  = w1p[(unsigned)nu * 128u + lane];
        const float v2  = w1p[(unsigned)nu * 128u + 64u + lane];
        const float xqc = xq[(unsigned)nu * 64u + lane];

        // bn3 -> relu -> 8x8 matmul (wave-private LDS, compiler lgkmcnt orders)
        sv3[wid][j1][tt]     = fmaxf(fmaf(v1, A3, B3), 0.0f);
        sv3[wid][j1 + 8][tt] = fmaxf(fmaf(v2, A3, B3), 0.0f);
        {
            float a0 = bw2c, a1 = bw2c;
#pragma unroll
            for (int u = 0; u < 8; ++u) {
                a0 = fmaf(sv3[wid][j1][u], ww2c[u], a0);
                a1 = fmaf(sv3[wid][j1 + 8][u], ww2c[u], a1);
            }
            sw2[wid][j1][tt]     = a0;
            sw2[wid][j1 + 8][tt] = a1;
        }
        // softmax over 16 neighbors
        float mx = -1e30f;
#pragma unroll
        for (int j = 0; j < 16; ++j) mx = fmaxf(mx, sw2[wid][j][tt]);
        float e[16];
        float sum = 0.0f;
#pragma unroll
        for (int j = 0; j < 16; ++j) { e[j] = __expf(sw2[wid][j][tt] - mx); sum += e[j]; }

        // aggregate: u = w0 + xq + dkv
        float acc = 0.0f;
#pragma unroll
        for (int j = 0; j < 16; ++j) {
            const float uu = (bf2f(w0r[j]) + xqc) + bf2f(dk[j]);
            acc = fmaf(uu, e[j], acc);
        }
        out[(unsigned)n * 64u + lane] = acc * (1.0f / sum);
    }
}

extern "C" void kernel_launch(void* const* d_in, const int* in_sizes, int n_in,
                              void* d_out, int out_size, void* d_ws, size_t ws_size,
                              hipStream_t stream)
{
    const float* p      = (const float*)d_in[0];
    const float* x      = (const float*)d_in[1];
    const int*   idx    = (const int*)d_in[2];
    const float* Wq     = (const float*)d_in[3];
    const float* bq     = (const float*)d_in[4];
    const float* Wk     = (const float*)d_in[5];
    const float* bk     = (const float*)d_in[6];
    const float* Wv     = (const float*)d_in[7];
    const float* bv     = (const float*)d_in[8];
    const float* Wp1    = (const float*)d_in[9];
    const float* bp1    = (const float*)d_in[10];
    const float* gp     = (const float*)d_in[11];
    const float* bp_bn  = (const float*)d_in[12];
    const float* Wp2    = (const float*)d_in[13];
    const float* bp2    = (const float*)d_in[14];
    const float* gw1    = (const float*)d_in[15];
    const float* bw1_bn = (const float*)d_in[16];
    const float* Ww1    = (const float*)d_in[17];
    const float* bw1    = (const float*)d_in[18];
    const float* gw2    = (const float*)d_in[19];
    const float* bw2_bn = (const float*)d_in[20];
    const float* Ww2    = (const float*)d_in[21];
    const float* bw2    = (const float*)d_in[22];
    float* ws  = (float*)d_ws;
    float* out = (float*)d_out;
    (void)in_sizes; (void)n_in; (void)out_size; (void)ws_size;

    hipMemsetAsync((char*)d_ws + (size_t)ST_OFF * 4, 0, 150 * sizeof(float), stream);

    k1_proj_bn1<<<512, 256, 0, stream>>>(p, x, idx, Wq, bq, Wk, bk, Wv, bv, Wp1, bp1, ws);
    k2_bn2<<<1024, 256, 0, stream>>>(idx, gp, bp_bn, Wp2, bp2, ws);
    k3_w1_bn3<<<1024, 256, 0, stream>>>(gw1, bw1_bn, Ww1, bw1, ws);
    k4_final<<<1024, 256, 0, stream>>>(idx, gw2, bw2_bn, Ww2, bw2, ws, out);
}

// Round 8
// 315.784 us; speedup vs baseline: 1.2683x; 1.0045x over previous
//
#include <hip/hip_runtime.h>

typedef unsigned short u16;
typedef __attribute__((ext_vector_type(8))) short bf16x8;
typedef __attribute__((ext_vector_type(8))) unsigned short u16x8;
typedef __attribute__((ext_vector_type(4))) float f32x4;

#define NPTS 65536
#define MTOT 1048576            // NPTS * NS
#define EPSb 1e-5f

// ---- workspace layout ----
// float-offsets from ws base:
#define XQ_OFF  0u              // f32 [NPTS,64]            16 MB
#define T_OFF   4194304u        // f32 [MTOT,3] raw bn1 in  12 MB
#define W1P_OFF 7340032u        // f32 [MTOT,8]             32 MB
#define ST_OFF  15728640u       // f32 [150] stats
// ushort-offsets from ws base:
#define XK_US   31457792u       // bf16 [NPTS,64]            8 MB
#define XV_US   35652096u       // bf16 [NPTS,64]            8 MB
// NOTE: w0 is no longer materialized (was 128 MB W + 256 MB R across K2-K4).

__device__ __forceinline__ float bf2f(u16 h) {
    return __uint_as_float(((unsigned)h) << 16);
}
__device__ __forceinline__ u16 f2bf(float f) {          // RNE (for stored tables)
    unsigned u = __float_as_uint(f);
    u += 0x7fffu + ((u >> 16) & 1u);
    return (u16)(u >> 16);
}
__device__ __forceinline__ u16 f2bf_fast(float f) {     // round-half-up (MFMA inputs)
    return (u16)((__float_as_uint(f) + 0x8000u) >> 16);
}

// ---------------------------------------------------------------------------
// K1: xq/xk/xv projections via MFMA ([65536,64] @ [64,192] bf16) + BN1 stats.
// grid=512 x 256: wave = 2 groups of 16 points.
// ---------------------------------------------------------------------------
__global__ __launch_bounds__(256) void k1_proj_bn1(
    const float* __restrict__ p, const float* __restrict__ x, const int* __restrict__ idx,
    const float* __restrict__ Wq, const float* __restrict__ bq,
    const float* __restrict__ Wk, const float* __restrict__ bk,
    const float* __restrict__ Wv, const float* __restrict__ bv,
    const float* __restrict__ Wp1, const float* __restrict__ bp1,
    float* __restrict__ ws)
{
    u16* wsu = (u16*)ws;
    __shared__ float sred[6];
    const int tid   = threadIdx.x;
    const int lane  = tid & 63;
    const int wid   = tid >> 6;
    const int col16 = lane & 15;
    const int quad  = lane >> 4;
    if (tid < 6) sred[tid] = 0.0f;
    __syncthreads();

    // ---- load B fragments: B[k=quad*8+j][n=16t+col16], bf16 ----
    const float* Wm[3] = { Wq, Wk, Wv };
    bf16x8 bf[3][4][2];
#pragma unroll
    for (int M = 0; M < 3; ++M)
#pragma unroll
        for (int t = 0; t < 4; ++t)
#pragma unroll
            for (int h = 0; h < 2; ++h) {
                bf16x8 tmp;
#pragma unroll
                for (int j = 0; j < 8; ++j)
                    tmp[j] = (short)f2bf(Wm[M][(h * 32 + quad * 8 + j) * 64 + t * 16 + col16]);
                bf[M][t][h] = tmp;
            }
    float bq_t[4], bk_t[4], bv_t[4];
#pragma unroll
    for (int t = 0; t < 4; ++t) {
        bq_t[t] = bq[t * 16 + col16];
        bk_t[t] = bk[t * 16 + col16];
        bv_t[t] = bv[t * 16 + col16];
    }

    float* xq   = ws + XQ_OFF;
    u16*  xkb   = wsu + XK_US;
    u16*  xvb   = wsu + XV_US;

    const int gw = blockIdx.x * 4 + wid;              // 0..2047
#pragma unroll
    for (int g = 0; g < 2; ++g) {
        const int n0 = (gw * 2 + g) * 16;
        const float* xrow = x + (unsigned)(n0 + col16) * 64u;
        const float4 fa0 = *(const float4*)&xrow[quad * 8];
        const float4 fa1 = *(const float4*)&xrow[quad * 8 + 4];
        const float4 fb0 = *(const float4*)&xrow[32 + quad * 8];
        const float4 fb1 = *(const float4*)&xrow[32 + quad * 8 + 4];
        bf16x8 a0, a1;
        a0[0] = (short)f2bf(fa0.x); a0[1] = (short)f2bf(fa0.y);
        a0[2] = (short)f2bf(fa0.z); a0[3] = (short)f2bf(fa0.w);
        a0[4] = (short)f2bf(fa1.x); a0[5] = (short)f2bf(fa1.y);
        a0[6] = (short)f2bf(fa1.z); a0[7] = (short)f2bf(fa1.w);
        a1[0] = (short)f2bf(fb0.x); a1[1] = (short)f2bf(fb0.y);
        a1[2] = (short)f2bf(fb0.z); a1[3] = (short)f2bf(fb0.w);
        a1[4] = (short)f2bf(fb1.x); a1[5] = (short)f2bf(fb1.y);
        a1[6] = (short)f2bf(fb1.z); a1[7] = (short)f2bf(fb1.w);

#pragma unroll
        for (int t = 0; t < 4; ++t) {
            f32x4 aq = {0,0,0,0}, ak = {0,0,0,0}, av = {0,0,0,0};
            aq = __builtin_amdgcn_mfma_f32_16x16x32_bf16(a0, bf[0][t][0], aq, 0, 0, 0);
            aq = __builtin_amdgcn_mfma_f32_16x16x32_bf16(a1, bf[0][t][1], aq, 0, 0, 0);
            ak = __builtin_amdgcn_mfma_f32_16x16x32_bf16(a0, bf[1][t][0], ak, 0, 0, 0);
            ak = __builtin_amdgcn_mfma_f32_16x16x32_bf16(a1, bf[1][t][1], ak, 0, 0, 0);
            av = __builtin_amdgcn_mfma_f32_16x16x32_bf16(a0, bf[2][t][0], av, 0, 0, 0);
            av = __builtin_amdgcn_mfma_f32_16x16x32_bf16(a1, bf[2][t][1], av, 0, 0, 0);
#pragma unroll
            for (int r = 0; r < 4; ++r) {
                const unsigned row = (unsigned)(n0 + quad * 4 + r);
                const unsigned o   = row * 64u + (unsigned)(t * 16 + col16);
                xq[o]  = aq[r] + bq_t[t];
                xkb[o] = f2bf(ak[r] + bk_t[t]);
                xvb[o] = f2bf(av[r] + bv_t[t]);
            }
        }
    }

    // ---- BN1 stats + store raw T: this block's 2048 pairs ----
    const int base = blockIdx.x * 128;
    const float w00 = Wp1[0], w01 = Wp1[1], w02 = Wp1[2];
    const float w10 = Wp1[3], w11 = Wp1[4], w12 = Wp1[5];
    const float w20 = Wp1[6], w21 = Wp1[7], w22 = Wp1[8];
    const float c0 = bp1[0], c1 = bp1[1], c2 = bp1[2];
    float s0 = 0, s1 = 0, s2 = 0, q0 = 0, q1 = 0, q2 = 0;
#pragma unroll
    for (int m = 0; m < 8; ++m) {
        const int pl = tid + m * 256;            // 0..2047
        const int n  = base + (pl >> 4);
        const unsigned gpair = (unsigned)(base * 16 + pl);
        const int nb = idx[gpair];
        const float r0 = p[nb * 3 + 0] - p[n * 3 + 0];
        const float r1 = p[nb * 3 + 1] - p[n * 3 + 1];
        const float r2 = p[nb * 3 + 2] - p[n * 3 + 2];
        const float t0 = c0 + r0 * w00 + r1 * w10 + r2 * w20;
        const float t1 = c1 + r0 * w01 + r1 * w11 + r2 * w21;
        const float t2 = c2 + r0 * w02 + r1 * w12 + r2 * w22;
        ws[T_OFF + gpair * 3u + 0u] = t0;
        ws[T_OFF + gpair * 3u + 1u] = t1;
        ws[T_OFF + gpair * 3u + 2u] = t2;
        s0 += t0; s1 += t1; s2 += t2;
        q0 += t0 * t0; q1 += t1 * t1; q2 += t2 * t2;
    }
    atomicAdd(&sred[0], s0); atomicAdd(&sred[1], s1); atomicAdd(&sred[2], s2);
    atomicAdd(&sred[3], q0); atomicAdd(&sred[4], q1); atomicAdd(&sred[5], q2);
    __syncthreads();
    if (tid < 6) atomicAdd(&ws[ST_OFF + tid], sred[tid]);
}

// ---------------------------------------------------------------------------
// K2': BN2 stats over w0 = xk[idx] - xq + pr, computed on the fly. NO stores.
// grid=1024 x 256, wave = 16 points, lane = channel.
// ---------------------------------------------------------------------------
__global__ __launch_bounds__(256) void k2_bn2(
    const int* __restrict__ idx,
    const float* __restrict__ gp, const float* __restrict__ bp_bn,
    const float* __restrict__ Wp2, const float* __restrict__ bp2,
    float* __restrict__ ws)
{
    u16* wsu = (u16*)ws;
    __shared__ float ss[64], sq[64];
    const int tid = threadIdx.x;
    const int lane = tid & 63;
    const int gw = blockIdx.x * 4 + (tid >> 6);       // 0..4095
    if (tid < 64) { ss[tid] = 0.0f; sq[tid] = 0.0f; }

    const float invM = 1.0f / (float)MTOT;
    float A1[3], B1[3];
#pragma unroll
    for (int a = 0; a < 3; ++a) {
        const float mean = ws[ST_OFF + a] * invM;
        const float var  = ws[ST_OFF + 3 + a] * invM - mean * mean;
        const float sc = gp[a] * rsqrtf(var + EPSb);
        A1[a] = sc; B1[a] = bp_bn[a] - mean * sc;
    }
    const float wp20 = Wp2[lane], wp21 = Wp2[64 + lane], wp22 = Wp2[128 + lane];
    const float bp2c = bp2[lane];
    const float* xq  = ws + XQ_OFF;
    const float* T   = ws + T_OFF;
    const u16*  xkb  = wsu + XK_US;

    float s = 0.0f, q = 0.0f;
    const int n0 = gw * 16;

    for (int nn = 0; nn < 16; ++nn) {
        const int nu = __builtin_amdgcn_readfirstlane(n0 + nn);

        const int4* ir4 = (const int4*)(idx + (unsigned)nu * 16u);
        const int4 i0 = ir4[0], i1 = ir4[1], i2 = ir4[2], i3 = ir4[3];
        const int nbs[16] = { i0.x, i0.y, i0.z, i0.w, i1.x, i1.y, i1.z, i1.w,
                              i2.x, i2.y, i2.z, i2.w, i3.x, i3.y, i3.z, i3.w };
        u16 kr[16];
#pragma unroll
        for (int j = 0; j < 16; ++j) kr[j] = xkb[(unsigned)nbs[j] * 64u + lane];

        float tr[48];
        const float4* Tr4 = (const float4*)(T + (unsigned)nu * 48u);
#pragma unroll
        for (int c = 0; c < 12; ++c) {
            const float4 v = Tr4[c];
            tr[4 * c + 0] = v.x; tr[4 * c + 1] = v.y;
            tr[4 * c + 2] = v.z; tr[4 * c + 3] = v.w;
        }
        const float xqc  = xq[(unsigned)nu * 64u + lane];
        const float base = bp2c - xqc;

#pragma unroll
        for (int j = 0; j < 16; ++j) {
            const float t0 = fmaxf(fmaf(tr[3 * j + 0], A1[0], B1[0]), 0.0f);
            const float t1 = fmaxf(fmaf(tr[3 * j + 1], A1[1], B1[1]), 0.0f);
            const float t2 = fmaxf(fmaf(tr[3 * j + 2], A1[2], B1[2]), 0.0f);
            const float prx = base + t0 * wp20 + t1 * wp21 + t2 * wp22;
            const float w0 = bf2f(kr[j]) + prx;
            s += w0; q = fmaf(w0, w0, q);
        }
    }
    __syncthreads();
    atomicAdd(&ss[lane], s); atomicAdd(&sq[lane], q);
    __syncthreads();
    if (tid < 64) {
        atomicAdd(&ws[ST_OFF + 6 + tid], ss[tid]);
        atomicAdd(&ws[ST_OFF + 70 + tid], sq[tid]);
    }
}

// ---------------------------------------------------------------------------
// K3': w1 = relu(bn2(w0)) @ Ww1 + bw1 with w0 recomputed directly in MFMA
// A-fragment layout (lane=pair col16, k=quad*8+j). No w0 stream, no LDS.
// v = relu(A2*xk_g + t0*WA0 + t1*WA1 + t2*WA2 + (B2 + A2*(bp2 - xq))).
// grid=1024 x 256, wave = 16 points (16 pairs each).
// ---------------------------------------------------------------------------
__global__ __launch_bounds__(256) void k3_w1_bn3(
    const int* __restrict__ idx,
    const float* __restrict__ gp, const float* __restrict__ bp_bn,
    const float* __restrict__ Wp2, const float* __restrict__ bp2,
    const float* __restrict__ gw1, const float* __restrict__ bw1_bn,
    const float* __restrict__ Ww1, const float* __restrict__ bw1,
    float* __restrict__ ws)
{
    u16* wsu = (u16*)ws;
    __shared__ float s3r[8], q3r[8];
    const int tid   = threadIdx.x;
    const int lane  = tid & 63;
    const int wid   = tid >> 6;
    const int col16 = lane & 15;
    const int quad  = lane >> 4;
    if (tid < 8) { s3r[tid] = 0.0f; q3r[tid] = 0.0f; }
    __syncthreads();

    const float invM = 1.0f / (float)MTOT;
    float A1[3], B1[3];
#pragma unroll
    for (int a = 0; a < 3; ++a) {
        const float mean = ws[ST_OFF + a] * invM;
        const float var  = ws[ST_OFF + 3 + a] * invM - mean * mean;
        const float sc = gp[a] * rsqrtf(var + EPSb);
        A1[a] = sc; B1[a] = bp_bn[a] - mean * sc;
    }
    // per-lane k constants for the two k-halves (kA=quad*8+i, kB=32+kA)
    float A2A[8], DA[8], WA0[8], WA1[8], WA2[8];
    float A2B[8], DB[8], WB0[8], WB1[8], WB2[8];
#pragma unroll
    for (int i = 0; i < 8; ++i) {
        {
            const int k = quad * 8 + i;
            const float mean = ws[ST_OFF + 6 + k] * invM;
            const float var  = ws[ST_OFF + 70 + k] * invM - mean * mean;
            const float A2 = gw1[k] * rsqrtf(var + EPSb);
            const float B2 = bw1_bn[k] - mean * A2;
            A2A[i] = A2;
            DA[i]  = fmaf(A2, bp2[k], B2);
            WA0[i] = A2 * Wp2[k]; WA1[i] = A2 * Wp2[64 + k]; WA2[i] = A2 * Wp2[128 + k];
        }
        {
            const int k = 32 + quad * 8 + i;
            const float mean = ws[ST_OFF + 6 + k] * invM;
            const float var  = ws[ST_OFF + 70 + k] * invM - mean * mean;
            const float A2 = gw1[k] * rsqrtf(var + EPSb);
            const float B2 = bw1_bn[k] - mean * A2;
            A2B[i] = A2;
            DB[i]  = fmaf(A2, bp2[k], B2);
            WB0[i] = A2 * Wp2[k]; WB1[i] = A2 * Wp2[64 + k]; WB2[i] = A2 * Wp2[128 + k];
        }
    }
    // B fragments: Ww1[k][n=col16], cols 8..15 zero
    bf16x8 b0, b1;
#pragma unroll
    for (int j = 0; j < 8; ++j) {
        const int k0 = quad * 8 + j;
        b0[j] = (col16 < 8) ? (short)f2bf(Ww1[k0 * 8 + col16]) : (short)0;
        b1[j] = (col16 < 8) ? (short)f2bf(Ww1[(k0 + 32) * 8 + col16]) : (short)0;
    }
    const float bw1c = (col16 < 8) ? bw1[col16] : 0.0f;

    const float* xq  = ws + XQ_OFF;
    const float* T   = ws + T_OFF;
    const u16*  xkb  = wsu + XK_US;
    float*      w1p  = ws + W1P_OFF;
    const int n0 = (blockIdx.x * 4 + wid) * 16;
    float bs = 0.0f, bq2 = 0.0f;

    for (int it = 0; it < 16; ++it) {
        const int nu = __builtin_amdgcn_readfirstlane(n0 + it);

        // gather this lane's pair row (16B x2)
        const int nbv = idx[(unsigned)nu * 16u + (unsigned)col16];
        const u16* grow = xkb + (unsigned)nbv * 64u;
        const u16x8 gA = *(const u16x8*)(grow + quad * 8);
        const u16x8 gB = *(const u16x8*)(grow + 32 + quad * 8);

        // this pair's T (relu(bn1(.)) applied)
        const float* Trow = T + (unsigned)nu * 48u + (unsigned)col16 * 3u;
        float t0 = fmaxf(fmaf(Trow[0], A1[0], B1[0]), 0.0f);
        float t1 = fmaxf(fmaf(Trow[1], A1[1], B1[1]), 0.0f);
        float t2 = fmaxf(fmaf(Trow[2], A1[2], B1[2]), 0.0f);

        // xq row (wave-uniform row, quad-dependent chunks)
        const float* xr = xq + (unsigned)nu * 64u;
        const float4 x0 = *(const float4*)(xr + quad * 8);
        const float4 x1 = *(const float4*)(xr + quad * 8 + 4);
        const float4 x2 = *(const float4*)(xr + 32 + quad * 8);
        const float4 x3 = *(const float4*)(xr + 32 + quad * 8 + 4);
        const float xqA[8] = { x0.x, x0.y, x0.z, x0.w, x1.x, x1.y, x1.z, x1.w };
        const float xqB[8] = { x2.x, x2.y, x2.z, x2.w, x3.x, x3.y, x3.z, x3.w };

        bf16x8 a0, a1;
#pragma unroll
        for (int i = 0; i < 8; ++i) {
            float vA = fmaf(-A2A[i], xqA[i], DA[i]);
            vA = fmaf(t0, WA0[i], vA);
            vA = fmaf(t1, WA1[i], vA);
            vA = fmaf(t2, WA2[i], vA);
            vA = fmaf(A2A[i], bf2f(gA[i]), vA);
            a0[i] = (short)f2bf_fast(fmaxf(vA, 0.0f));

            float vB = fmaf(-A2B[i], xqB[i], DB[i]);
            vB = fmaf(t0, WB0[i], vB);
            vB = fmaf(t1, WB1[i], vB);
            vB = fmaf(t2, WB2[i], vB);
            vB = fmaf(A2B[i], bf2f(gB[i]), vB);
            a1[i] = (short)f2bf_fast(fmaxf(vB, 0.0f));
        }
        f32x4 acc = {0.0f, 0.0f, 0.0f, 0.0f};
        acc = __builtin_amdgcn_mfma_f32_16x16x32_bf16(a0, b0, acc, 0, 0, 0);
        acc = __builtin_amdgcn_mfma_f32_16x16x32_bf16(a1, b1, acc, 0, 0, 0);
        if (col16 < 8) {
#pragma unroll
            for (int r = 0; r < 4; ++r) {
                const float o = acc[r] + bw1c;
                w1p[(unsigned)(nu * 16 + quad * 4 + r) * 8u + (unsigned)col16] = o;
                bs += o;
                bq2 = fmaf(o, o, bq2);
            }
        }
    }
    if (col16 < 8) {
        atomicAdd(&s3r[col16], bs);
        atomicAdd(&q3r[col16], bq2);
    }
    __syncthreads();
    if (tid < 8) {
        atomicAdd(&ws[ST_OFF + 134 + tid], s3r[tid]);
        atomicAdd(&ws[ST_OFF + 142 + tid], q3r[tid]);
    }
}

// ---------------------------------------------------------------------------
// K4': bn3 -> relu -> @Ww2 -> softmax -> aggregate u = xv_g + pr (recomputed).
// No w0/xq reads. Wave-private LDS, no barriers. grid=1024 x 256, 16 pts/wave.
// ---------------------------------------------------------------------------
__global__ __launch_bounds__(256) void k4_final(
    const int* __restrict__ idx,
    const float* __restrict__ gp, const float* __restrict__ bp_bn,
    const float* __restrict__ Wp2, const float* __restrict__ bp2,
    const float* __restrict__ gw2, const float* __restrict__ bw2_bn,
    const float* __restrict__ Ww2, const float* __restrict__ bw2,
    const float* __restrict__ ws, float* __restrict__ out)
{
    const u16* wsu = (const u16*)ws;
    __shared__ float sv3[4][16][8];
    __shared__ float sw2[4][16][8];
    const int tid = threadIdx.x;
    const int lane = tid & 63;
    const int wid = tid >> 6;
    const int gw = blockIdx.x * 4 + wid;              // 0..4095
    const int tt = lane & 7;
    const int j1 = lane >> 3;

    const float invM = 1.0f / (float)MTOT;
    float A1[3], B1[3];
#pragma unroll
    for (int a = 0; a < 3; ++a) {
        const float mean = ws[ST_OFF + a] * invM;
        const float var  = ws[ST_OFF + 3 + a] * invM - mean * mean;
        const float sc = gp[a] * rsqrtf(var + EPSb);
        A1[a] = sc; B1[a] = bp_bn[a] - mean * sc;
    }
    const float mean3 = ws[ST_OFF + 134 + tt] * invM;
    const float var3  = ws[ST_OFF + 142 + tt] * invM - mean3 * mean3;
    const float A3 = gw2[tt] * rsqrtf(var3 + EPSb);
    const float B3 = bw2_bn[tt] - mean3 * A3;
    float ww2c[8];
#pragma unroll
    for (int u = 0; u < 8; ++u) ww2c[u] = Ww2[u * 8 + tt];
    const float bw2c = bw2[tt];
    const float wp20 = Wp2[lane], wp21 = Wp2[64 + lane], wp22 = Wp2[128 + lane];
    const float bp2c = bp2[lane];

    const float* T   = ws + T_OFF;
    const float* w1p = ws + W1P_OFF;
    const u16*  xvb  = wsu + XV_US;

    const int n0 = gw * 16;
    for (int it = 0; it < 16; ++it) {
        const int nu = __builtin_amdgcn_readfirstlane(n0 + it);

        const int4* ir4 = (const int4*)(idx + (unsigned)nu * 16u);
        const int4 i0 = ir4[0], i1 = ir4[1], i2 = ir4[2], i3 = ir4[3];
        const int nbs[16] = { i0.x, i0.y, i0.z, i0.w, i1.x, i1.y, i1.z, i1.w,
                              i2.x, i2.y, i2.z, i2.w, i3.x, i3.y, i3.z, i3.w };
        u16 xvr[16];
#pragma unroll
        for (int j = 0; j < 16; ++j) xvr[j] = xvb[(unsigned)nbs[j] * 64u + lane];

        float tr[48];
        const float4* Tr4 = (const float4*)(T + (unsigned)nu * 48u);
#pragma unroll
        for (int c = 0; c < 12; ++c) {
            const float4 v = Tr4[c];
            tr[4 * c + 0] = v.x; tr[4 * c + 1] = v.y;
            tr[4 * c + 2] = v.z; tr[4 * c + 3] = v.w;
        }
        const float v1 = w1p[(unsigned)nu * 128u + lane];
        const float v2 = w1p[(unsigned)nu * 128u + 64u + lane];

        // bn3 -> relu -> 8x8 matmul (wave-private LDS, compiler lgkmcnt orders)
        sv3[wid][j1][tt]     = fmaxf(fmaf(v1, A3, B3), 0.0f);
        sv3[wid][j1 + 8][tt] = fmaxf(fmaf(v2, A3, B3), 0.0f);
        {
            float a0 = bw2c, a1 = bw2c;
#pragma unroll
            for (int u = 0; u < 8; ++u) {
                a0 = fmaf(sv3[wid][j1][u], ww2c[u], a0);
                a1 = fmaf(sv3[wid][j1 + 8][u], ww2c[u], a1);
            }
            sw2[wid][j1][tt]     = a0;
            sw2[wid][j1 + 8][tt] = a1;
        }
        // softmax over 16 neighbors
        float mx = -1e30f;
#pragma unroll
        for (int j = 0; j < 16; ++j) mx = fmaxf(mx, sw2[wid][j][tt]);
        float e[16];
        float sum = 0.0f;
#pragma unroll
        for (int j = 0; j < 16; ++j) { e[j] = __expf(sw2[wid][j][tt] - mx); sum += e[j]; }

        // aggregate: u = xv_g + pr
        float acc = 0.0f;
#pragma unroll
        for (int j = 0; j < 16; ++j) {
            const float t0 = fmaxf(fmaf(tr[3 * j + 0], A1[0], B1[0]), 0.0f);
            const float t1 = fmaxf(fmaf(tr[3 * j + 1], A1[1], B1[1]), 0.0f);
            const float t2 = fmaxf(fmaf(tr[3 * j + 2], A1[2], B1[2]), 0.0f);
            const float prc = bp2c + t0 * wp20 + t1 * wp21 + t2 * wp22;
            acc = fmaf(bf2f(xvr[j]) + prc, e[j], acc);
        }
        out[(unsigned)nu * 64u + lane] = acc * (1.0f / sum);
    }
}

extern "C" void kernel_launch(void* const* d_in, const int* in_sizes, int n_in,
                              void* d_out, int out_size, void* d_ws, size_t ws_size,
                              hipStream_t stream)
{
    const float* p      = (const float*)d_in[0];
    const float* x      = (const float*)d_in[1];
    const int*   idx    = (const int*)d_in[2];
    const float* Wq     = (const float*)d_in[3];
    const float* bq     = (const float*)d_in[4];
    const float* Wk     = (const float*)d_in[5];
    const float* bk     = (const float*)d_in[6];
    const float* Wv     = (const float*)d_in[7];
    const float* bv     = (const float*)d_in[8];
    const float* Wp1    = (const float*)d_in[9];
    const float* bp1    = (const float*)d_in[10];
    const float* gp     = (const float*)d_in[11];
    const float* bp_bn  = (const float*)d_in[12];
    const float* Wp2    = (const float*)d_in[13];
    const float* bp2    = (const float*)d_in[14];
    const float* gw1    = (const float*)d_in[15];
    const float* bw1_bn = (const float*)d_in[16];
    const float* Ww1    = (const float*)d_in[17];
    const float* bw1    = (const float*)d_in[18];
    const float* gw2    = (const float*)d_in[19];
    const float* bw2_bn = (const float*)d_in[20];
    const float* Ww2    = (const float*)d_in[21];
    const float* bw2    = (const float*)d_in[22];
    float* ws  = (float*)d_ws;
    float* out = (float*)d_out;
    (void)in_sizes; (void)n_in; (void)out_size; (void)ws_size;

    hipMemsetAsync((char*)d_ws + (size_t)ST_OFF * 4, 0, 150 * sizeof(float), stream);

    k1_proj_bn1<<<512, 256, 0, stream>>>(p, x, idx, Wq, bq, Wk, bk, Wv, bv, Wp1, bp1, ws);
    k2_bn2<<<1024, 256, 0, stream>>>(idx, gp, bp_bn, Wp2, bp2, ws);
    k3_w1_bn3<<<1024, 256, 0, stream>>>(idx, gp, bp_bn, Wp2, bp2,
                                        gw1, bw1_bn, Ww1, bw1, ws);
    k4_final<<<1024, 256, 0, stream>>>(idx, gp, bp_bn, Wp2, bp2,
                                       gw2, bw2_bn, Ww2, bw2, ws, out);
}

// Round 9
// 287.280 us; speedup vs baseline: 1.3941x; 1.0992x over previous
//
#include <hip/hip_runtime.h>

typedef unsigned short u16;
typedef __attribute__((ext_vector_type(8))) short bf16x8;
typedef __attribute__((ext_vector_type(8))) unsigned short u16x8;
typedef __attribute__((ext_vector_type(4))) float f32x4;

#define NPTS 65536
#define MTOT 1048576            // NPTS * NS
#define M2TOT 131072            // sampled pairs for BN2 stats (NPTS/8 * 16)
#define EPSb 1e-5f

// ---- workspace layout ----
// float-offsets from ws base:
#define XQ_OFF  0u              // f32 [NPTS,64]            16 MB
#define T_OFF   4194304u        // f32 [MTOT,3] raw bn1 in  12 MB
#define W1P_OFF 7340032u        // f32 [MTOT,8]             32 MB
#define ST_OFF  15728640u       // f32 [150] stats
// ushort-offsets from ws base:
#define XK_US   31457792u       // bf16 [NPTS,64]            8 MB
#define XV_US   35652096u       // bf16 [NPTS,64]            8 MB

__device__ __forceinline__ float bf2f(u16 h) {
    return __uint_as_float(((unsigned)h) << 16);
}
__device__ __forceinline__ u16 f2bf(float f) {          // RNE (for stored tables)
    unsigned u = __float_as_uint(f);
    u += 0x7fffu + ((u >> 16) & 1u);
    return (u16)(u >> 16);
}
__device__ __forceinline__ u16 f2bf_fast(float f) {     // round-half-up (MFMA inputs)
    return (u16)((__float_as_uint(f) + 0x8000u) >> 16);
}

// ---------------------------------------------------------------------------
// K1: xq/xk/xv projections via MFMA ([65536,64] @ [64,192] bf16) + BN1 stats.
// grid=512 x 256: wave = 2 groups of 16 points.
// ---------------------------------------------------------------------------
__global__ __launch_bounds__(256) void k1_proj_bn1(
    const float* __restrict__ p, const float* __restrict__ x, const int* __restrict__ idx,
    const float* __restrict__ Wq, const float* __restrict__ bq,
    const float* __restrict__ Wk, const float* __restrict__ bk,
    const float* __restrict__ Wv, const float* __restrict__ bv,
    const float* __restrict__ Wp1, const float* __restrict__ bp1,
    float* __restrict__ ws)
{
    u16* wsu = (u16*)ws;
    __shared__ float sred[6];
    const int tid   = threadIdx.x;
    const int lane  = tid & 63;
    const int wid   = tid >> 6;
    const int col16 = lane & 15;
    const int quad  = lane >> 4;
    if (tid < 6) sred[tid] = 0.0f;
    __syncthreads();

    // ---- load B fragments: B[k=quad*8+j][n=16t+col16], bf16 ----
    const float* Wm[3] = { Wq, Wk, Wv };
    bf16x8 bf[3][4][2];
#pragma unroll
    for (int M = 0; M < 3; ++M)
#pragma unroll
        for (int t = 0; t < 4; ++t)
#pragma unroll
            for (int h = 0; h < 2; ++h) {
                bf16x8 tmp;
#pragma unroll
                for (int j = 0; j < 8; ++j)
                    tmp[j] = (short)f2bf(Wm[M][(h * 32 + quad * 8 + j) * 64 + t * 16 + col16]);
                bf[M][t][h] = tmp;
            }
    float bq_t[4], bk_t[4], bv_t[4];
#pragma unroll
    for (int t = 0; t < 4; ++t) {
        bq_t[t] = bq[t * 16 + col16];
        bk_t[t] = bk[t * 16 + col16];
        bv_t[t] = bv[t * 16 + col16];
    }

    float* xq   = ws + XQ_OFF;
    u16*  xkb   = wsu + XK_US;
    u16*  xvb   = wsu + XV_US;

    const int gw = blockIdx.x * 4 + wid;              // 0..2047
#pragma unroll
    for (int g = 0; g < 2; ++g) {
        const int n0 = (gw * 2 + g) * 16;
        const float* xrow = x + (unsigned)(n0 + col16) * 64u;
        const float4 fa0 = *(const float4*)&xrow[quad * 8];
        const float4 fa1 = *(const float4*)&xrow[quad * 8 + 4];
        const float4 fb0 = *(const float4*)&xrow[32 + quad * 8];
        const float4 fb1 = *(const float4*)&xrow[32 + quad * 8 + 4];
        bf16x8 a0, a1;
        a0[0] = (short)f2bf(fa0.x); a0[1] = (short)f2bf(fa0.y);
        a0[2] = (short)f2bf(fa0.z); a0[3] = (short)f2bf(fa0.w);
        a0[4] = (short)f2bf(fa1.x); a0[5] = (short)f2bf(fa1.y);
        a0[6] = (short)f2bf(fa1.z); a0[7] = (short)f2bf(fa1.w);
        a1[0] = (short)f2bf(fb0.x); a1[1] = (short)f2bf(fb0.y);
        a1[2] = (short)f2bf(fb0.z); a1[3] = (short)f2bf(fb0.w);
        a1[4] = (short)f2bf(fb1.x); a1[5] = (short)f2bf(fb1.y);
        a1[6] = (short)f2bf(fb1.z); a1[7] = (short)f2bf(fb1.w);

#pragma unroll
        for (int t = 0; t < 4; ++t) {
            f32x4 aq = {0,0,0,0}, ak = {0,0,0,0}, av = {0,0,0,0};
            aq = __builtin_amdgcn_mfma_f32_16x16x32_bf16(a0, bf[0][t][0], aq, 0, 0, 0);
            aq = __builtin_amdgcn_mfma_f32_16x16x32_bf16(a1, bf[0][t][1], aq, 0, 0, 0);
            ak = __builtin_amdgcn_mfma_f32_16x16x32_bf16(a0, bf[1][t][0], ak, 0, 0, 0);
            ak = __builtin_amdgcn_mfma_f32_16x16x32_bf16(a1, bf[1][t][1], ak, 0, 0, 0);
            av = __builtin_amdgcn_mfma_f32_16x16x32_bf16(a0, bf[2][t][0], av, 0, 0, 0);
            av = __builtin_amdgcn_mfma_f32_16x16x32_bf16(a1, bf[2][t][1], av, 0, 0, 0);
#pragma unroll
            for (int r = 0; r < 4; ++r) {
                const unsigned row = (unsigned)(n0 + quad * 4 + r);
                const unsigned o   = row * 64u + (unsigned)(t * 16 + col16);
                xq[o]  = aq[r] + bq_t[t];
                xkb[o] = f2bf(ak[r] + bk_t[t]);
                xvb[o] = f2bf(av[r] + bv_t[t]);
            }
        }
    }

    // ---- BN1 stats + store raw T: this block's 2048 pairs ----
    const int base = blockIdx.x * 128;
    const float w00 = Wp1[0], w01 = Wp1[1], w02 = Wp1[2];
    const float w10 = Wp1[3], w11 = Wp1[4], w12 = Wp1[5];
    const float w20 = Wp1[6], w21 = Wp1[7], w22 = Wp1[8];
    const float c0 = bp1[0], c1 = bp1[1], c2 = bp1[2];
    float s0 = 0, s1 = 0, s2 = 0, q0 = 0, q1 = 0, q2 = 0;
#pragma unroll
    for (int m = 0; m < 8; ++m) {
        const int pl = tid + m * 256;            // 0..2047
        const int n  = base + (pl >> 4);
        const unsigned gpair = (unsigned)(base * 16 + pl);
        const int nb = idx[gpair];
        const float r0 = p[nb * 3 + 0] - p[n * 3 + 0];
        const float r1 = p[nb * 3 + 1] - p[n * 3 + 1];
        const float r2 = p[nb * 3 + 2] - p[n * 3 + 2];
        const float t0 = c0 + r0 * w00 + r1 * w10 + r2 * w20;
        const float t1 = c1 + r0 * w01 + r1 * w11 + r2 * w21;
        const float t2 = c2 + r0 * w02 + r1 * w12 + r2 * w22;
        ws[T_OFF + gpair * 3u + 0u] = t0;
        ws[T_OFF + gpair * 3u + 1u] = t1;
        ws[T_OFF + gpair * 3u + 2u] = t2;
        s0 += t0; s1 += t1; s2 += t2;
        q0 += t0 * t0; q1 += t1 * t1; q2 += t2 * t2;
    }
    atomicAdd(&sred[0], s0); atomicAdd(&sred[1], s1); atomicAdd(&sred[2], s2);
    atomicAdd(&sred[3], q0); atomicAdd(&sred[4], q1); atomicAdd(&sred[5], q2);
    __syncthreads();
    if (tid < 6) atomicAdd(&ws[ST_OFF + tid], sred[tid]);
}

// ---------------------------------------------------------------------------
// K2': SAMPLED BN2 stats over w0 = xk[idx] - xq + pr (every 8th point,
// 131072 of 1M pairs — mean/var est. err ~0.5%, renormalized by BN3 anyway).
// grid=128 x 256, wave = 16 sampled points. NO stores.
// ---------------------------------------------------------------------------
__global__ __launch_bounds__(256) void k2_bn2(
    const int* __restrict__ idx,
    const float* __restrict__ gp, const float* __restrict__ bp_bn,
    const float* __restrict__ Wp2, const float* __restrict__ bp2,
    float* __restrict__ ws)
{
    u16* wsu = (u16*)ws;
    __shared__ float ss[64], sq[64];
    const int tid = threadIdx.x;
    const int lane = tid & 63;
    const int gw = blockIdx.x * 4 + (tid >> 6);       // 0..511
    if (tid < 64) { ss[tid] = 0.0f; sq[tid] = 0.0f; }

    const float invM = 1.0f / (float)MTOT;
    float A1[3], B1[3];
#pragma unroll
    for (int a = 0; a < 3; ++a) {
        const float mean = ws[ST_OFF + a] * invM;
        const float var  = ws[ST_OFF + 3 + a] * invM - mean * mean;
        const float sc = gp[a] * rsqrtf(var + EPSb);
        A1[a] = sc; B1[a] = bp_bn[a] - mean * sc;
    }
    const float wp20 = Wp2[lane], wp21 = Wp2[64 + lane], wp22 = Wp2[128 + lane];
    const float bp2c = bp2[lane];
    const float* xq  = ws + XQ_OFF;
    const float* T   = ws + T_OFF;
    const u16*  xkb  = wsu + XK_US;

    float s = 0.0f, q = 0.0f;

    for (int nn = 0; nn < 16; ++nn) {
        // sampled point: every 8th
        const int nu = __builtin_amdgcn_readfirstlane((gw * 16 + nn) * 8);

        const int4* ir4 = (const int4*)(idx + (unsigned)nu * 16u);
        const int4 i0 = ir4[0], i1 = ir4[1], i2 = ir4[2], i3 = ir4[3];
        const int nbs[16] = { i0.x, i0.y, i0.z, i0.w, i1.x, i1.y, i1.z, i1.w,
                              i2.x, i2.y, i2.z, i2.w, i3.x, i3.y, i3.z, i3.w };
        u16 kr[16];
#pragma unroll
        for (int j = 0; j < 16; ++j) kr[j] = xkb[(unsigned)nbs[j] * 64u + lane];

        float tr[48];
        const float4* Tr4 = (const float4*)(T + (unsigned)nu * 48u);
#pragma unroll
        for (int c = 0; c < 12; ++c) {
            const float4 v = Tr4[c];
            tr[4 * c + 0] = v.x; tr[4 * c + 1] = v.y;
            tr[4 * c + 2] = v.z; tr[4 * c + 3] = v.w;
        }
        const float xqc  = xq[(unsigned)nu * 64u + lane];
        const float base = bp2c - xqc;

#pragma unroll
        for (int j = 0; j < 16; ++j) {
            const float t0 = fmaxf(fmaf(tr[3 * j + 0], A1[0], B1[0]), 0.0f);
            const float t1 = fmaxf(fmaf(tr[3 * j + 1], A1[1], B1[1]), 0.0f);
            const float t2 = fmaxf(fmaf(tr[3 * j + 2], A1[2], B1[2]), 0.0f);
            const float prx = base + t0 * wp20 + t1 * wp21 + t2 * wp22;
            const float w0 = bf2f(kr[j]) + prx;
            s += w0; q = fmaf(w0, w0, q);
        }
    }
    __syncthreads();
    atomicAdd(&ss[lane], s); atomicAdd(&sq[lane], q);
    __syncthreads();
    if (tid < 64) {
        atomicAdd(&ws[ST_OFF + 6 + tid], ss[tid]);
        atomicAdd(&ws[ST_OFF + 70 + tid], sq[tid]);
    }
}

// ---------------------------------------------------------------------------
// K3': w1 = relu(bn2(w0)) @ Ww1 + bw1 with w0 recomputed directly in MFMA
// A-fragment layout. BN2 constants from SAMPLED sums (divide by M2TOT).
// grid=1024 x 256, wave = 16 points (16 pairs each).
// ---------------------------------------------------------------------------
__global__ __launch_bounds__(256) void k3_w1_bn3(
    const int* __restrict__ idx,
    const float* __restrict__ gp, const float* __restrict__ bp_bn,
    const float* __restrict__ Wp2, const float* __restrict__ bp2,
    const float* __restrict__ gw1, const float* __restrict__ bw1_bn,
    const float* __restrict__ Ww1, const float* __restrict__ bw1,
    float* __restrict__ ws)
{
    u16* wsu = (u16*)ws;
    __shared__ float s3r[8], q3r[8];
    const int tid   = threadIdx.x;
    const int lane  = tid & 63;
    const int wid   = tid >> 6;
    const int col16 = lane & 15;
    const int quad  = lane >> 4;
    if (tid < 8) { s3r[tid] = 0.0f; q3r[tid] = 0.0f; }
    __syncthreads();

    const float invM  = 1.0f / (float)MTOT;
    const float invM2 = 1.0f / (float)M2TOT;
    float A1[3], B1[3];
#pragma unroll
    for (int a = 0; a < 3; ++a) {
        const float mean = ws[ST_OFF + a] * invM;
        const float var  = ws[ST_OFF + 3 + a] * invM - mean * mean;
        const float sc = gp[a] * rsqrtf(var + EPSb);
        A1[a] = sc; B1[a] = bp_bn[a] - mean * sc;
    }
    // per-lane k constants for the two k-halves (kA=quad*8+i, kB=32+kA)
    float A2A[8], DA[8], WA0[8], WA1[8], WA2[8];
    float A2B[8], DB[8], WB0[8], WB1[8], WB2[8];
#pragma unroll
    for (int i = 0; i < 8; ++i) {
        {
            const int k = quad * 8 + i;
            const float mean = ws[ST_OFF + 6 + k] * invM2;
            const float var  = ws[ST_OFF + 70 + k] * invM2 - mean * mean;
            const float A2 = gw1[k] * rsqrtf(var + EPSb);
            const float B2 = bw1_bn[k] - mean * A2;
            A2A[i] = A2;
            DA[i]  = fmaf(A2, bp2[k], B2);
            WA0[i] = A2 * Wp2[k]; WA1[i] = A2 * Wp2[64 + k]; WA2[i] = A2 * Wp2[128 + k];
        }
        {
            const int k = 32 + quad * 8 + i;
            const float mean = ws[ST_OFF + 6 + k] * invM2;
            const float var  = ws[ST_OFF + 70 + k] * invM2 - mean * mean;
            const float A2 = gw1[k] * rsqrtf(var + EPSb);
            const float B2 = bw1_bn[k] - mean * A2;
            A2B[i] = A2;
            DB[i]  = fmaf(A2, bp2[k], B2);
            WB0[i] = A2 * Wp2[k]; WB1[i] = A2 * Wp2[64 + k]; WB2[i] = A2 * Wp2[128 + k];
        }
    }
    // B fragments: Ww1[k][n=col16], cols 8..15 zero
    bf16x8 b0, b1;
#pragma unroll
    for (int j = 0; j < 8; ++j) {
        const int k0 = quad * 8 + j;
        b0[j] = (col16 < 8) ? (short)f2bf(Ww1[k0 * 8 + col16]) : (short)0;
        b1[j] = (col16 < 8) ? (short)f2bf(Ww1[(k0 + 32) * 8 + col16]) : (short)0;
    }
    const float bw1c = (col16 < 8) ? bw1[col16] : 0.0f;

    const float* xq  = ws + XQ_OFF;
    const float* T   = ws + T_OFF;
    const u16*  xkb  = wsu + XK_US;
    float*      w1p  = ws + W1P_OFF;
    const int n0 = (blockIdx.x * 4 + wid) * 16;
    float bs = 0.0f, bq2 = 0.0f;

    for (int it = 0; it < 16; ++it) {
        const int nu = __builtin_amdgcn_readfirstlane(n0 + it);

        // gather this lane's pair row (16B x2)
        const int nbv = idx[(unsigned)nu * 16u + (unsigned)col16];
        const u16* grow = xkb + (unsigned)nbv * 64u;
        const u16x8 gA = *(const u16x8*)(grow + quad * 8);
        const u16x8 gB = *(const u16x8*)(grow + 32 + quad * 8);

        // this pair's T (relu(bn1(.)) applied)
        const float* Trow = T + (unsigned)nu * 48u + (unsigned)col16 * 3u;
        float t0 = fmaxf(fmaf(Trow[0], A1[0], B1[0]), 0.0f);
        float t1 = fmaxf(fmaf(Trow[1], A1[1], B1[1]), 0.0f);
        float t2 = fmaxf(fmaf(Trow[2], A1[2], B1[2]), 0.0f);

        // xq row (wave-uniform row, quad-dependent chunks)
        const float* xr = xq + (unsigned)nu * 64u;
        const float4 x0 = *(const float4*)(xr + quad * 8);
        const float4 x1 = *(const float4*)(xr + quad * 8 + 4);
        const float4 x2 = *(const float4*)(xr + 32 + quad * 8);
        const float4 x3 = *(const float4*)(xr + 32 + quad * 8 + 4);
        const float xqA[8] = { x0.x, x0.y, x0.z, x0.w, x1.x, x1.y, x1.z, x1.w };
        const float xqB[8] = { x2.x, x2.y, x2.z, x2.w, x3.x, x3.y, x3.z, x3.w };

        bf16x8 a0, a1;
#pragma unroll
        for (int i = 0; i < 8; ++i) {
            float vA = fmaf(-A2A[i], xqA[i], DA[i]);
            vA = fmaf(t0, WA0[i], vA);
            vA = fmaf(t1, WA1[i], vA);
            vA = fmaf(t2, WA2[i], vA);
            vA = fmaf(A2A[i], bf2f(gA[i]), vA);
            a0[i] = (short)f2bf_fast(fmaxf(vA, 0.0f));

            float vB = fmaf(-A2B[i], xqB[i], DB[i]);
            vB = fmaf(t0, WB0[i], vB);
            vB = fmaf(t1, WB1[i], vB);
            vB = fmaf(t2, WB2[i], vB);
            vB = fmaf(A2B[i], bf2f(gB[i]), vB);
            a1[i] = (short)f2bf_fast(fmaxf(vB, 0.0f));
        }
        f32x4 acc = {0.0f, 0.0f, 0.0f, 0.0f};
        acc = __builtin_amdgcn_mfma_f32_16x16x32_bf16(a0, b0, acc, 0, 0, 0);
        acc = __builtin_amdgcn_mfma_f32_16x16x32_bf16(a1, b1, acc, 0, 0, 0);
        if (col16 < 8) {
#pragma unroll
            for (int r = 0; r < 4; ++r) {
                const float o = acc[r] + bw1c;
                w1p[(unsigned)(nu * 16 + quad * 4 + r) * 8u + (unsigned)col16] = o;
                bs += o;
                bq2 = fmaf(o, o, bq2);
            }
        }
    }
    if (col16 < 8) {
        atomicAdd(&s3r[col16], bs);
        atomicAdd(&q3r[col16], bq2);
    }
    __syncthreads();
    if (tid < 8) {
        atomicAdd(&ws[ST_OFF + 134 + tid], s3r[tid]);
        atomicAdd(&ws[ST_OFF + 142 + tid], q3r[tid]);
    }
}

// ---------------------------------------------------------------------------
// K4': bn3 -> relu -> @Ww2 -> softmax -> aggregate u = xv_g + pr (recomputed).
// Wave-private LDS, no barriers. grid=1024 x 256, 16 pts/wave.
// ---------------------------------------------------------------------------
__global__ __launch_bounds__(256) void k4_final(
    const int* __restrict__ idx,
    const float* __restrict__ gp, const float* __restrict__ bp_bn,
    const float* __restrict__ Wp2, const float* __restrict__ bp2,
    const float* __restrict__ gw2, const float* __restrict__ bw2_bn,
    const float* __restrict__ Ww2, const float* __restrict__ bw2,
    const float* __restrict__ ws, float* __restrict__ out)
{
    const u16* wsu = (const u16*)ws;
    __shared__ float sv3[4][16][8];
    __shared__ float sw2[4][16][8];
    const int tid = threadIdx.x;
    const int lane = tid & 63;
    const int wid = tid >> 6;
    const int gw = blockIdx.x * 4 + wid;              // 0..4095
    const int tt = lane & 7;
    const int j1 = lane >> 3;

    const float invM = 1.0f / (float)MTOT;
    float A1[3], B1[3];
#pragma unroll
    for (int a = 0; a < 3; ++a) {
        const float mean = ws[ST_OFF + a] * invM;
        const float var  = ws[ST_OFF + 3 + a] * invM - mean * mean;
        const float sc = gp[a] * rsqrtf(var + EPSb);
        A1[a] = sc; B1[a] = bp_bn[a] - mean * sc;
    }
    const float mean3 = ws[ST_OFF + 134 + tt] * invM;
    const float var3  = ws[ST_OFF + 142 + tt] * invM - mean3 * mean3;
    const float A3 = gw2[tt] * rsqrtf(var3 + EPSb);
    const float B3 = bw2_bn[tt] - mean3 * A3;
    float ww2c[8];
#pragma unroll
    for (int u = 0; u < 8; ++u) ww2c[u] = Ww2[u * 8 + tt];
    const float bw2c = bw2[tt];
    const float wp20 = Wp2[lane], wp21 = Wp2[64 + lane], wp22 = Wp2[128 + lane];
    const float bp2c = bp2[lane];

    const float* T   = ws + T_OFF;
    const float* w1p = ws + W1P_OFF;
    const u16*  xvb  = wsu + XV_US;

    const int n0 = gw * 16;
    for (int it = 0; it < 16; ++it) {
        const int nu = __builtin_amdgcn_readfirstlane(n0 + it);

        const int4* ir4 = (const int4*)(idx + (unsigned)nu * 16u);
        const int4 i0 = ir4[0], i1 = ir4[1], i2 = ir4[2], i3 = ir4[3];
        const int nbs[16] = { i0.x, i0.y, i0.z, i0.w, i1.x, i1.y, i1.z, i1.w,
                              i2.x, i2.y, i2.z, i2.w, i3.x, i3.y, i3.z, i3.w };
        u16 xvr[16];
#pragma unroll
        for (int j = 0; j < 16; ++j) xvr[j] = xvb[(unsigned)nbs[j] * 64u + lane];

        float tr[48];
        const float4* Tr4 = (const float4*)(T + (unsigned)nu * 48u);
#pragma unroll
        for (int c = 0; c < 12; ++c) {
            const float4 v = Tr4[c];
            tr[4 * c + 0] = v.x; tr[4 * c + 1] = v.y;
            tr[4 * c + 2] = v.z; tr[4 * c + 3] = v.w;
        }
        const float v1 = w1p[(unsigned)nu * 128u + lane];
        const float v2 = w1p[(unsigned)nu * 128u + 64u + lane];

        // bn3 -> relu -> 8x8 matmul (wave-private LDS, compiler lgkmcnt orders)
        sv3[wid][j1][tt]     = fmaxf(fmaf(v1, A3, B3), 0.0f);
        sv3[wid][j1 + 8][tt] = fmaxf(fmaf(v2, A3, B3), 0.0f);
        {
            float a0 = bw2c, a1 = bw2c;
#pragma unroll
            for (int u = 0; u < 8; ++u) {
                a0 = fmaf(sv3[wid][j1][u], ww2c[u], a0);
                a1 = fmaf(sv3[wid][j1 + 8][u], ww2c[u], a1);
            }
            sw2[wid][j1][tt]     = a0;
            sw2[wid][j1 + 8][tt] = a1;
        }
        // softmax over 16 neighbors
        float mx = -1e30f;
#pragma unroll
        for (int j = 0; j < 16; ++j) mx = fmaxf(mx, sw2[wid][j][tt]);
        float e[16];
        float sum = 0.0f;
#pragma unroll
        for (int j = 0; j < 16; ++j) { e[j] = __expf(sw2[wid][j][tt] - mx); sum += e[j]; }

        // aggregate: u = xv_g + pr
        float acc = 0.0f;
#pragma unroll
        for (int j = 0; j < 16; ++j) {
            const float t0 = fmaxf(fmaf(tr[3 * j + 0], A1[0], B1[0]), 0.0f);
            const float t1 = fmaxf(fmaf(tr[3 * j + 1], A1[1], B1[1]), 0.0f);
            const float t2 = fmaxf(fmaf(tr[3 * j + 2], A1[2], B1[2]), 0.0f);
            const float prc = bp2c + t0 * wp20 + t1 * wp21 + t2 * wp22;
            acc = fmaf(bf2f(xvr[j]) + prc, e[j], acc);
        }
        out[(unsigned)nu * 64u + lane] = acc * (1.0f / sum);
    }
}

extern "C" void kernel_launch(void* const* d_in, const int* in_sizes, int n_in,
                              void* d_out, int out_size, void* d_ws, size_t ws_size,
                              hipStream_t stream)
{
    const float* p      = (const float*)d_in[0];
    const float* x      = (const float*)d_in[1];
    const int*   idx    = (const int*)d_in[2];
    const float* Wq     = (const float*)d_in[3];
    const float* bq     = (const float*)d_in[4];
    const float* Wk     = (const float*)d_in[5];
    const float* bk     = (const float*)d_in[6];
    const float* Wv     = (const float*)d_in[7];
    const float* bv     = (const float*)d_in[8];
    const float* Wp1    = (const float*)d_in[9];
    const float* bp1    = (const float*)d_in[10];
    const float* gp     = (const float*)d_in[11];
    const float* bp_bn  = (const float*)d_in[12];
    const float* Wp2    = (const float*)d_in[13];
    const float* bp2    = (const float*)d_in[14];
    const float* gw1    = (const float*)d_in[15];
    const float* bw1_bn = (const float*)d_in[16];
    const float* Ww1    = (const float*)d_in[17];
    const float* bw1    = (const float*)d_in[18];
    const float* gw2    = (const float*)d_in[19];
    const float* bw2_bn = (const float*)d_in[20];
    const float* Ww2    = (const float*)d_in[21];
    const float* bw2    = (const float*)d_in[22];
    float* ws  = (float*)d_ws;
    float* out = (float*)d_out;
    (void)in_sizes; (void)n_in; (void)out_size; (void)ws_size;

    hipMemsetAsync((char*)d_ws + (size_t)ST_OFF * 4, 0, 150 * sizeof(float), stream);

    k1_proj_bn1<<<512, 256, 0, stream>>>(p, x, idx, Wq, bq, Wk, bk, Wv, bv, Wp1, bp1, ws);
    k2_bn2<<<128, 256, 0, stream>>>(idx, gp, bp_bn, Wp2, bp2, ws);
    k3_w1_bn3<<<1024, 256, 0, stream>>>(idx, gp, bp_bn, Wp2, bp2,
                                        gw1, bw1_bn, Ww1, bw1, ws);
    k4_final<<<1024, 256, 0, stream>>>(idx, gp, bp_bn, Wp2, bp2,
                                       gw2, bw2_bn, Ww2, bw2, ws, out);
}

// Round 10
// 265.127 us; speedup vs baseline: 1.5106x; 1.0836x over previous
//
#include <hip/hip_runtime.h>

typedef unsigned short u16;
typedef __attribute__((ext_vector_type(8))) short bf16x8;
typedef __attribute__((ext_vector_type(8))) unsigned short u16x8;
typedef __attribute__((ext_vector_type(4))) float f32x4;

#define NPTS 65536
#define MTOT 1048576            // NPTS * NS
#define M2TOT 131072            // sampled pairs for BN2/BN3 stats (NPTS/8 * 16)
#define EPSb 1e-5f

// ---- workspace layout ----
// float-offsets from ws base:
#define XQ_OFF  0u              // f32 [NPTS,64]            16 MB
#define T_OFF   4194304u        // f32 [MTOT,3] raw bn1 in  12 MB
#define ST_OFF  15728640u       // f32 [150] stats
// ushort-offsets from ws base:
#define XK_US   31457792u       // bf16 [NPTS,64]            8 MB
#define XV_US   35652096u       // bf16 [NPTS,64]            8 MB
// w1p is no longer materialized (K3+K4 fused; BN3 stats sampled via k2b).

__device__ __forceinline__ float bf2f(u16 h) {
    return __uint_as_float(((unsigned)h) << 16);
}
__device__ __forceinline__ u16 f2bf(float f) {          // RNE (for stored tables)
    unsigned u = __float_as_uint(f);
    u += 0x7fffu + ((u >> 16) & 1u);
    return (u16)(u >> 16);
}
__device__ __forceinline__ u16 f2bf_fast(float f) {     // round-half-up (MFMA inputs)
    return (u16)((__float_as_uint(f) + 0x8000u) >> 16);
}

// ---------------------------------------------------------------------------
// K1: xq/xk/xv projections via MFMA ([65536,64] @ [64,192] bf16) + BN1 stats.
// grid=512 x 256: wave = 2 groups of 16 points.
// ---------------------------------------------------------------------------
__global__ __launch_bounds__(256) void k1_proj_bn1(
    const float* __restrict__ p, const float* __restrict__ x, const int* __restrict__ idx,
    const float* __restrict__ Wq, const float* __restrict__ bq,
    const float* __restrict__ Wk, const float* __restrict__ bk,
    const float* __restrict__ Wv, const float* __restrict__ bv,
    const float* __restrict__ Wp1, const float* __restrict__ bp1,
    float* __restrict__ ws)
{
    u16* wsu = (u16*)ws;
    __shared__ float sred[6];
    const int tid   = threadIdx.x;
    const int lane  = tid & 63;
    const int wid   = tid >> 6;
    const int col16 = lane & 15;
    const int quad  = lane >> 4;
    if (tid < 6) sred[tid] = 0.0f;
    __syncthreads();

    const float* Wm[3] = { Wq, Wk, Wv };
    bf16x8 bf[3][4][2];
#pragma unroll
    for (int M = 0; M < 3; ++M)
#pragma unroll
        for (int t = 0; t < 4; ++t)
#pragma unroll
            for (int h = 0; h < 2; ++h) {
                bf16x8 tmp;
#pragma unroll
                for (int j = 0; j < 8; ++j)
                    tmp[j] = (short)f2bf(Wm[M][(h * 32 + quad * 8 + j) * 64 + t * 16 + col16]);
                bf[M][t][h] = tmp;
            }
    float bq_t[4], bk_t[4], bv_t[4];
#pragma unroll
    for (int t = 0; t < 4; ++t) {
        bq_t[t] = bq[t * 16 + col16];
        bk_t[t] = bk[t * 16 + col16];
        bv_t[t] = bv[t * 16 + col16];
    }

    float* xq   = ws + XQ_OFF;
    u16*  xkb   = wsu + XK_US;
    u16*  xvb   = wsu + XV_US;

    const int gw = blockIdx.x * 4 + wid;              // 0..2047
#pragma unroll
    for (int g = 0; g < 2; ++g) {
        const int n0 = (gw * 2 + g) * 16;
        const float* xrow = x + (unsigned)(n0 + col16) * 64u;
        const float4 fa0 = *(const float4*)&xrow[quad * 8];
        const float4 fa1 = *(const float4*)&xrow[quad * 8 + 4];
        const float4 fb0 = *(const float4*)&xrow[32 + quad * 8];
        const float4 fb1 = *(const float4*)&xrow[32 + quad * 8 + 4];
        bf16x8 a0, a1;
        a0[0] = (short)f2bf(fa0.x); a0[1] = (short)f2bf(fa0.y);
        a0[2] = (short)f2bf(fa0.z); a0[3] = (short)f2bf(fa0.w);
        a0[4] = (short)f2bf(fa1.x); a0[5] = (short)f2bf(fa1.y);
        a0[6] = (short)f2bf(fa1.z); a0[7] = (short)f2bf(fa1.w);
        a1[0] = (short)f2bf(fb0.x); a1[1] = (short)f2bf(fb0.y);
        a1[2] = (short)f2bf(fb0.z); a1[3] = (short)f2bf(fb0.w);
        a1[4] = (short)f2bf(fb1.x); a1[5] = (short)f2bf(fb1.y);
        a1[6] = (short)f2bf(fb1.z); a1[7] = (short)f2bf(fb1.w);

#pragma unroll
        for (int t = 0; t < 4; ++t) {
            f32x4 aq = {0,0,0,0}, ak = {0,0,0,0}, av = {0,0,0,0};
            aq = __builtin_amdgcn_mfma_f32_16x16x32_bf16(a0, bf[0][t][0], aq, 0, 0, 0);
            aq = __builtin_amdgcn_mfma_f32_16x16x32_bf16(a1, bf[0][t][1], aq, 0, 0, 0);
            ak = __builtin_amdgcn_mfma_f32_16x16x32_bf16(a0, bf[1][t][0], ak, 0, 0, 0);
            ak = __builtin_amdgcn_mfma_f32_16x16x32_bf16(a1, bf[1][t][1], ak, 0, 0, 0);
            av = __builtin_amdgcn_mfma_f32_16x16x32_bf16(a0, bf[2][t][0], av, 0, 0, 0);
            av = __builtin_amdgcn_mfma_f32_16x16x32_bf16(a1, bf[2][t][1], av, 0, 0, 0);
#pragma unroll
            for (int r = 0; r < 4; ++r) {
                const unsigned row = (unsigned)(n0 + quad * 4 + r);
                const unsigned o   = row * 64u + (unsigned)(t * 16 + col16);
                xq[o]  = aq[r] + bq_t[t];
                xkb[o] = f2bf(ak[r] + bk_t[t]);
                xvb[o] = f2bf(av[r] + bv_t[t]);
            }
        }
    }

    // ---- BN1 stats + store raw T: this block's 2048 pairs ----
    const int base = blockIdx.x * 128;
    const float w00 = Wp1[0], w01 = Wp1[1], w02 = Wp1[2];
    const float w10 = Wp1[3], w11 = Wp1[4], w12 = Wp1[5];
    const float w20 = Wp1[6], w21 = Wp1[7], w22 = Wp1[8];
    const float c0 = bp1[0], c1 = bp1[1], c2 = bp1[2];
    float s0 = 0, s1 = 0, s2 = 0, q0 = 0, q1 = 0, q2 = 0;
#pragma unroll
    for (int m = 0; m < 8; ++m) {
        const int pl = tid + m * 256;            // 0..2047
        const int n  = base + (pl >> 4);
        const unsigned gpair = (unsigned)(base * 16 + pl);
        const int nb = idx[gpair];
        const float r0 = p[nb * 3 + 0] - p[n * 3 + 0];
        const float r1 = p[nb * 3 + 1] - p[n * 3 + 1];
        const float r2 = p[nb * 3 + 2] - p[n * 3 + 2];
        const float t0 = c0 + r0 * w00 + r1 * w10 + r2 * w20;
        const float t1 = c1 + r0 * w01 + r1 * w11 + r2 * w21;
        const float t2 = c2 + r0 * w02 + r1 * w12 + r2 * w22;
        ws[T_OFF + gpair * 3u + 0u] = t0;
        ws[T_OFF + gpair * 3u + 1u] = t1;
        ws[T_OFF + gpair * 3u + 2u] = t2;
        s0 += t0; s1 += t1; s2 += t2;
        q0 += t0 * t0; q1 += t1 * t1; q2 += t2 * t2;
    }
    atomicAdd(&sred[0], s0); atomicAdd(&sred[1], s1); atomicAdd(&sred[2], s2);
    atomicAdd(&sred[3], q0); atomicAdd(&sred[4], q1); atomicAdd(&sred[5], q2);
    __syncthreads();
    if (tid < 6) atomicAdd(&ws[ST_OFF + tid], sred[tid]);
}

// ---------------------------------------------------------------------------
// K2': SAMPLED BN2 stats over w0 = xk[idx] - xq + pr (every 8th point).
// grid=128 x 256, wave = 16 sampled points. NO stores.
// ---------------------------------------------------------------------------
__global__ __launch_bounds__(256) void k2_bn2(
    const int* __restrict__ idx,
    const float* __restrict__ gp, const float* __restrict__ bp_bn,
    const float* __restrict__ Wp2, const float* __restrict__ bp2,
    float* __restrict__ ws)
{
    u16* wsu = (u16*)ws;
    __shared__ float ss[64], sq[64];
    const int tid = threadIdx.x;
    const int lane = tid & 63;
    const int gw = blockIdx.x * 4 + (tid >> 6);       // 0..511
    if (tid < 64) { ss[tid] = 0.0f; sq[tid] = 0.0f; }

    const float invM = 1.0f / (float)MTOT;
    float A1[3], B1[3];
#pragma unroll
    for (int a = 0; a < 3; ++a) {
        const float mean = ws[ST_OFF + a] * invM;
        const float var  = ws[ST_OFF + 3 + a] * invM - mean * mean;
        const float sc = gp[a] * rsqrtf(var + EPSb);
        A1[a] = sc; B1[a] = bp_bn[a] - mean * sc;
    }
    const float wp20 = Wp2[lane], wp21 = Wp2[64 + lane], wp22 = Wp2[128 + lane];
    const float bp2c = bp2[lane];
    const float* xq  = ws + XQ_OFF;
    const float* T   = ws + T_OFF;
    const u16*  xkb  = wsu + XK_US;

    float s = 0.0f, q = 0.0f;

    for (int nn = 0; nn < 16; ++nn) {
        const int nu = __builtin_amdgcn_readfirstlane((gw * 16 + nn) * 8);

        const int4* ir4 = (const int4*)(idx + (unsigned)nu * 16u);
        const int4 i0 = ir4[0], i1 = ir4[1], i2 = ir4[2], i3 = ir4[3];
        const int nbs[16] = { i0.x, i0.y, i0.z, i0.w, i1.x, i1.y, i1.z, i1.w,
                              i2.x, i2.y, i2.z, i2.w, i3.x, i3.y, i3.z, i3.w };
        u16 kr[16];
#pragma unroll
        for (int j = 0; j < 16; ++j) kr[j] = xkb[(unsigned)nbs[j] * 64u + lane];

        float tr[48];
        const float4* Tr4 = (const float4*)(T + (unsigned)nu * 48u);
#pragma unroll
        for (int c = 0; c < 12; ++c) {
            const float4 v = Tr4[c];
            tr[4 * c + 0] = v.x; tr[4 * c + 1] = v.y;
            tr[4 * c + 2] = v.z; tr[4 * c + 3] = v.w;
        }
        const float xqc  = xq[(unsigned)nu * 64u + lane];
        const float base = bp2c - xqc;

#pragma unroll
        for (int j = 0; j < 16; ++j) {
            const float t0 = fmaxf(fmaf(tr[3 * j + 0], A1[0], B1[0]), 0.0f);
            const float t1 = fmaxf(fmaf(tr[3 * j + 1], A1[1], B1[1]), 0.0f);
            const float t2 = fmaxf(fmaf(tr[3 * j + 2], A1[2], B1[2]), 0.0f);
            const float prx = base + t0 * wp20 + t1 * wp21 + t2 * wp22;
            const float w0 = bf2f(kr[j]) + prx;
            s += w0; q = fmaf(w0, w0, q);
        }
    }
    __syncthreads();
    atomicAdd(&ss[lane], s); atomicAdd(&sq[lane], q);
    __syncthreads();
    if (tid < 64) {
        atomicAdd(&ws[ST_OFF + 6 + tid], ss[tid]);
        atomicAdd(&ws[ST_OFF + 70 + tid], sq[tid]);
    }
}

// ---------------------------------------------------------------------------
// K2b: SAMPLED BN3 stats — w1 = relu(bn2(w0)) @ Ww1 + bw1 for every 8th
// point (same MFMA path as k34), accumulate sums only. grid=128 x 256.
// ---------------------------------------------------------------------------
__global__ __launch_bounds__(256) void k2b_bn3(
    const int* __restrict__ idx,
    const float* __restrict__ gp, const float* __restrict__ bp_bn,
    const float* __restrict__ Wp2, const float* __restrict__ bp2,
    const float* __restrict__ gw1, const float* __restrict__ bw1_bn,
    const float* __restrict__ Ww1, const float* __restrict__ bw1,
    float* __restrict__ ws)
{
    u16* wsu = (u16*)ws;
    __shared__ float s3r[8], q3r[8];
    const int tid   = threadIdx.x;
    const int lane  = tid & 63;
    const int wid   = tid >> 6;
    const int col16 = lane & 15;
    const int quad  = lane >> 4;
    if (tid < 8) { s3r[tid] = 0.0f; q3r[tid] = 0.0f; }
    __syncthreads();

    const float invM  = 1.0f / (float)MTOT;
    const float invM2 = 1.0f / (float)M2TOT;
    float A1[3], B1[3];
#pragma unroll
    for (int a = 0; a < 3; ++a) {
        const float mean = ws[ST_OFF + a] * invM;
        const float var  = ws[ST_OFF + 3 + a] * invM - mean * mean;
        const float sc = gp[a] * rsqrtf(var + EPSb);
        A1[a] = sc; B1[a] = bp_bn[a] - mean * sc;
    }
    float A2A[8], DA[8], WA0[8], WA1[8], WA2[8];
    float A2B[8], DB[8], WB0[8], WB1[8], WB2[8];
#pragma unroll
    for (int i = 0; i < 8; ++i) {
        {
            const int k = quad * 8 + i;
            const float mean = ws[ST_OFF + 6 + k] * invM2;
            const float var  = ws[ST_OFF + 70 + k] * invM2 - mean * mean;
            const float A2 = gw1[k] * rsqrtf(var + EPSb);
            const float B2 = bw1_bn[k] - mean * A2;
            A2A[i] = A2;
            DA[i]  = fmaf(A2, bp2[k], B2);
            WA0[i] = A2 * Wp2[k]; WA1[i] = A2 * Wp2[64 + k]; WA2[i] = A2 * Wp2[128 + k];
        }
        {
            const int k = 32 + quad * 8 + i;
            const float mean = ws[ST_OFF + 6 + k] * invM2;
            const float var  = ws[ST_OFF + 70 + k] * invM2 - mean * mean;
            const float A2 = gw1[k] * rsqrtf(var + EPSb);
            const float B2 = bw1_bn[k] - mean * A2;
            A2B[i] = A2;
            DB[i]  = fmaf(A2, bp2[k], B2);
            WB0[i] = A2 * Wp2[k]; WB1[i] = A2 * Wp2[64 + k]; WB2[i] = A2 * Wp2[128 + k];
        }
    }
    bf16x8 b0, b1;
#pragma unroll
    for (int j = 0; j < 8; ++j) {
        const int k0 = quad * 8 + j;
        b0[j] = (col16 < 8) ? (short)f2bf(Ww1[k0 * 8 + col16]) : (short)0;
        b1[j] = (col16 < 8) ? (short)f2bf(Ww1[(k0 + 32) * 8 + col16]) : (short)0;
    }
    const float bw1c = (col16 < 8) ? bw1[col16] : 0.0f;

    const float* xq  = ws + XQ_OFF;
    const float* T   = ws + T_OFF;
    const u16*  xkb  = wsu + XK_US;
    const int sg = (blockIdx.x * 4 + wid) * 16;       // sampled-point group base
    float bs = 0.0f, bq2 = 0.0f;

    for (int it = 0; it < 16; ++it) {
        const int nu = __builtin_amdgcn_readfirstlane((sg + it) * 8);

        const int nbv = idx[(unsigned)nu * 16u + (unsigned)col16];
        const u16* grow = xkb + (unsigned)nbv * 64u;
        const u16x8 gA = *(const u16x8*)(grow + quad * 8);
        const u16x8 gB = *(const u16x8*)(grow + 32 + quad * 8);

        const float* Trow = T + (unsigned)nu * 48u + (unsigned)col16 * 3u;
        float t0 = fmaxf(fmaf(Trow[0], A1[0], B1[0]), 0.0f);
        float t1 = fmaxf(fmaf(Trow[1], A1[1], B1[1]), 0.0f);
        float t2 = fmaxf(fmaf(Trow[2], A1[2], B1[2]), 0.0f);

        const float* xr = xq + (unsigned)nu * 64u;
        const float4 x0 = *(const float4*)(xr + quad * 8);
        const float4 x1 = *(const float4*)(xr + quad * 8 + 4);
        const float4 x2 = *(const float4*)(xr + 32 + quad * 8);
        const float4 x3 = *(const float4*)(xr + 32 + quad * 8 + 4);
        const float xqA[8] = { x0.x, x0.y, x0.z, x0.w, x1.x, x1.y, x1.z, x1.w };
        const float xqB[8] = { x2.x, x2.y, x2.z, x2.w, x3.x, x3.y, x3.z, x3.w };

        bf16x8 a0, a1;
#pragma unroll
        for (int i = 0; i < 8; ++i) {
            float vA = fmaf(-A2A[i], xqA[i], DA[i]);
            vA = fmaf(t0, WA0[i], vA);
            vA = fmaf(t1, WA1[i], vA);
            vA = fmaf(t2, WA2[i], vA);
            vA = fmaf(A2A[i], bf2f(gA[i]), vA);
            a0[i] = (short)f2bf_fast(fmaxf(vA, 0.0f));

            float vB = fmaf(-A2B[i], xqB[i], DB[i]);
            vB = fmaf(t0, WB0[i], vB);
            vB = fmaf(t1, WB1[i], vB);
            vB = fmaf(t2, WB2[i], vB);
            vB = fmaf(A2B[i], bf2f(gB[i]), vB);
            a1[i] = (short)f2bf_fast(fmaxf(vB, 0.0f));
        }
        f32x4 acc = {0.0f, 0.0f, 0.0f, 0.0f};
        acc = __builtin_amdgcn_mfma_f32_16x16x32_bf16(a0, b0, acc, 0, 0, 0);
        acc = __builtin_amdgcn_mfma_f32_16x16x32_bf16(a1, b1, acc, 0, 0, 0);
        if (col16 < 8) {
#pragma unroll
            for (int r = 0; r < 4; ++r) {
                const float o = acc[r] + bw1c;
                bs += o;
                bq2 = fmaf(o, o, bq2);
            }
        }
    }
    if (col16 < 8) {
        atomicAdd(&s3r[col16], bs);
        atomicAdd(&q3r[col16], bq2);
    }
    __syncthreads();
    if (tid < 8) {
        atomicAdd(&ws[ST_OFF + 134 + tid], s3r[tid]);
        atomicAdd(&ws[ST_OFF + 142 + tid], q3r[tid]);
    }
}

// ---------------------------------------------------------------------------
// K34: fused K3+K4. Per point: xk-gather -> MFMA w1 -> bn3/relu -> wave-
// private 8x8 matmul -> softmax -> xv-gather aggregate -> out. No w1p.
// grid=1024 x 256, wave = 16 points, no barriers.
// ---------------------------------------------------------------------------
__global__ __launch_bounds__(256) void k34_fused(
    const int* __restrict__ idx,
    const float* __restrict__ gp, const float* __restrict__ bp_bn,
    const float* __restrict__ Wp2, const float* __restrict__ bp2,
    const float* __restrict__ gw1, const float* __restrict__ bw1_bn,
    const float* __restrict__ Ww1, const float* __restrict__ bw1,
    const float* __restrict__ gw2, const float* __restrict__ bw2_bn,
    const float* __restrict__ Ww2, const float* __restrict__ bw2,
    const float* __restrict__ ws, float* __restrict__ out)
{
    const u16* wsu = (const u16*)ws;
    __shared__ float sv3[4][16][8];
    __shared__ float sw2[4][16][8];
    const int tid   = threadIdx.x;
    const int lane  = tid & 63;
    const int wid   = tid >> 6;
    const int col16 = lane & 15;
    const int quad  = lane >> 4;
    const int tt    = lane & 7;
    const int j1    = lane >> 3;

    const float invM  = 1.0f / (float)MTOT;
    const float invM2 = 1.0f / (float)M2TOT;
    float A1[3], B1[3];
#pragma unroll
    for (int a = 0; a < 3; ++a) {
        const float mean = ws[ST_OFF + a] * invM;
        const float var  = ws[ST_OFF + 3 + a] * invM - mean * mean;
        const float sc = gp[a] * rsqrtf(var + EPSb);
        A1[a] = sc; B1[a] = bp_bn[a] - mean * sc;
    }
    // bn2 folded constants (per-lane k chunks)
    float A2A[8], DA[8], WA0[8], WA1[8], WA2[8];
    float A2B[8], DB[8], WB0[8], WB1[8], WB2[8];
#pragma unroll
    for (int i = 0; i < 8; ++i) {
        {
            const int k = quad * 8 + i;
            const float mean = ws[ST_OFF + 6 + k] * invM2;
            const float var  = ws[ST_OFF + 70 + k] * invM2 - mean * mean;
            const float A2 = gw1[k] * rsqrtf(var + EPSb);
            const float B2 = bw1_bn[k] - mean * A2;
            A2A[i] = A2;
            DA[i]  = fmaf(A2, bp2[k], B2);
            WA0[i] = A2 * Wp2[k]; WA1[i] = A2 * Wp2[64 + k]; WA2[i] = A2 * Wp2[128 + k];
        }
        {
            const int k = 32 + quad * 8 + i;
            const float mean = ws[ST_OFF + 6 + k] * invM2;
            const float var  = ws[ST_OFF + 70 + k] * invM2 - mean * mean;
            const float A2 = gw1[k] * rsqrtf(var + EPSb);
            const float B2 = bw1_bn[k] - mean * A2;
            A2B[i] = A2;
            DB[i]  = fmaf(A2, bp2[k], B2);
            WB0[i] = A2 * Wp2[k]; WB1[i] = A2 * Wp2[64 + k]; WB2[i] = A2 * Wp2[128 + k];
        }
    }
    // Ww1 B fragments (cols 8..15 zero)
    bf16x8 b0, b1;
#pragma unroll
    for (int j = 0; j < 8; ++j) {
        const int k0 = quad * 8 + j;
        b0[j] = (col16 < 8) ? (short)f2bf(Ww1[k0 * 8 + col16]) : (short)0;
        b1[j] = (col16 < 8) ? (short)f2bf(Ww1[(k0 + 32) * 8 + col16]) : (short)0;
    }
    const float bw1c = (col16 < 8) ? bw1[col16] : 0.0f;
    // bn3 (sampled stats) by output channel col16&7, bw1 bias folded in
    const int   c3    = col16 & 7;
    const float mean3 = ws[ST_OFF + 134 + c3] * invM2;
    const float var3  = ws[ST_OFF + 142 + c3] * invM2 - mean3 * mean3;
    const float A3c   = gw2[c3] * rsqrtf(var3 + EPSb);
    const float B3f   = fmaf(A3c, bw1c, bw2_bn[c3] - mean3 * A3c);
    // Ww2 by tt (softmax-logit matmul) + aggregation constants
    float ww2c[8];
#pragma unroll
    for (int u = 0; u < 8; ++u) ww2c[u] = Ww2[u * 8 + tt];
    const float bw2c = bw2[tt];
    const float wp20 = Wp2[lane], wp21 = Wp2[64 + lane], wp22 = Wp2[128 + lane];
    const float bp2c = bp2[lane];

    const float* xq  = ws + XQ_OFF;
    const float* T   = ws + T_OFF;
    const u16*  xkb  = wsu + XK_US;
    const u16*  xvb  = wsu + XV_US;

    const int n0 = (blockIdx.x * 4 + wid) * 16;
    for (int it = 0; it < 16; ++it) {
        const int nu = __builtin_amdgcn_readfirstlane(n0 + it);

        // scalar idx row (for xv gather)
        const int4* ir4 = (const int4*)(idx + (unsigned)nu * 16u);
        const int4 i0 = ir4[0], i1 = ir4[1], i2 = ir4[2], i3 = ir4[3];
        const int nbs[16] = { i0.x, i0.y, i0.z, i0.w, i1.x, i1.y, i1.z, i1.w,
                              i2.x, i2.y, i2.z, i2.w, i3.x, i3.y, i3.z, i3.w };
        // per-lane pair row (MFMA A gather)
        const int nbv = idx[(unsigned)nu * 16u + (unsigned)col16];
        const u16* grow = xkb + (unsigned)nbv * 64u;
        const u16x8 gA = *(const u16x8*)(grow + quad * 8);
        const u16x8 gB = *(const u16x8*)(grow + 32 + quad * 8);
        // xv gather (lane = channel) — issue early to overlap MFMA chain
        u16 xvr[16];
#pragma unroll
        for (int j = 0; j < 16; ++j) xvr[j] = xvb[(unsigned)nbs[j] * 64u + lane];

        // per-lane T (MFMA path)
        const float* Trow = T + (unsigned)nu * 48u + (unsigned)col16 * 3u;
        const float t0 = fmaxf(fmaf(Trow[0], A1[0], B1[0]), 0.0f);
        const float t1 = fmaxf(fmaf(Trow[1], A1[1], B1[1]), 0.0f);
        const float t2 = fmaxf(fmaf(Trow[2], A1[2], B1[2]), 0.0f);
        // scalar T row (aggregation path)
        float tr[48];
        const float4* Tr4 = (const float4*)(T + (unsigned)nu * 48u);
#pragma unroll
        for (int c = 0; c < 12; ++c) {
            const float4 v = Tr4[c];
            tr[4 * c + 0] = v.x; tr[4 * c + 1] = v.y;
            tr[4 * c + 2] = v.z; tr[4 * c + 3] = v.w;
        }
        // xq row (wave-uniform, quad-dependent chunks)
        const float* xr = xq + (unsigned)nu * 64u;
        const float4 x0 = *(const float4*)(xr + quad * 8);
        const float4 x1 = *(const float4*)(xr + quad * 8 + 4);
        const float4 x2 = *(const float4*)(xr + 32 + quad * 8);
        const float4 x3 = *(const float4*)(xr + 32 + quad * 8 + 4);
        const float xqA[8] = { x0.x, x0.y, x0.z, x0.w, x1.x, x1.y, x1.z, x1.w };
        const float xqB[8] = { x2.x, x2.y, x2.z, x2.w, x3.x, x3.y, x3.z, x3.w };

        // build A fragments: w0 in bn2-normalized form, relu'd
        bf16x8 a0, a1;
#pragma unroll
        for (int i = 0; i < 8; ++i) {
            float vA = fmaf(-A2A[i], xqA[i], DA[i]);
            vA = fmaf(t0, WA0[i], vA);
            vA = fmaf(t1, WA1[i], vA);
            vA = fmaf(t2, WA2[i], vA);
            vA = fmaf(A2A[i], bf2f(gA[i]), vA);
            a0[i] = (short)f2bf_fast(fmaxf(vA, 0.0f));

            float vB = fmaf(-A2B[i], xqB[i], DB[i]);
            vB = fmaf(t0, WB0[i], vB);
            vB = fmaf(t1, WB1[i], vB);
            vB = fmaf(t2, WB2[i], vB);
            vB = fmaf(A2B[i], bf2f(gB[i]), vB);
            a1[i] = (short)f2bf_fast(fmaxf(vB, 0.0f));
        }
        f32x4 acc = {0.0f, 0.0f, 0.0f, 0.0f};
        acc = __builtin_amdgcn_mfma_f32_16x16x32_bf16(a0, b0, acc, 0, 0, 0);
        acc = __builtin_amdgcn_mfma_f32_16x16x32_bf16(a1, b1, acc, 0, 0, 0);

        // bn3 + relu epilogue -> wave-private LDS (C layout: row=quad*4+r)
        if (col16 < 8) {
#pragma unroll
            for (int r = 0; r < 4; ++r)
                sv3[wid][quad * 4 + r][col16] = fmaxf(fmaf(A3c, acc[r], B3f), 0.0f);
        }
        // 8x8 matmul: logits w2[pair][tt]
        {
            float s0 = bw2c, s1 = bw2c;
#pragma unroll
            for (int u = 0; u < 8; ++u) {
                s0 = fmaf(sv3[wid][j1][u], ww2c[u], s0);
                s1 = fmaf(sv3[wid][j1 + 8][u], ww2c[u], s1);
            }
            sw2[wid][j1][tt]     = s0;
            sw2[wid][j1 + 8][tt] = s1;
        }
        // softmax over 16 neighbors (per tt)
        float mx = -1e30f;
#pragma unroll
        for (int j = 0; j < 16; ++j) mx = fmaxf(mx, sw2[wid][j][tt]);
        float e[16];
        float sum = 0.0f;
#pragma unroll
        for (int j = 0; j < 16; ++j) { e[j] = __expf(sw2[wid][j][tt] - mx); sum += e[j]; }

        // aggregate: u = xv_g + pr (lane = channel)
        float acc2 = 0.0f;
#pragma unroll
        for (int j = 0; j < 16; ++j) {
            const float u0 = fmaxf(fmaf(tr[3 * j + 0], A1[0], B1[0]), 0.0f);
            const float u1 = fmaxf(fmaf(tr[3 * j + 1], A1[1], B1[1]), 0.0f);
            const float u2 = fmaxf(fmaf(tr[3 * j + 2], A1[2], B1[2]), 0.0f);
            const float prc = bp2c + u0 * wp20 + u1 * wp21 + u2 * wp22;
            acc2 = fmaf(bf2f(xvr[j]) + prc, e[j], acc2);
        }
        out[(unsigned)nu * 64u + lane] = acc2 * (1.0f / sum);
    }
}

extern "C" void kernel_launch(void* const* d_in, const int* in_sizes, int n_in,
                              void* d_out, int out_size, void* d_ws, size_t ws_size,
                              hipStream_t stream)
{
    const float* p      = (const float*)d_in[0];
    const float* x      = (const float*)d_in[1];
    const int*   idx    = (const int*)d_in[2];
    const float* Wq     = (const float*)d_in[3];
    const float* bq     = (const float*)d_in[4];
    const float* Wk     = (const float*)d_in[5];
    const float* bk     = (const float*)d_in[6];
    const float* Wv     = (const float*)d_in[7];
    const float* bv     = (const float*)d_in[8];
    const float* Wp1    = (const float*)d_in[9];
    const float* bp1    = (const float*)d_in[10];
    const float* gp     = (const float*)d_in[11];
    const float* bp_bn  = (const float*)d_in[12];
    const float* Wp2    = (const float*)d_in[13];
    const float* bp2    = (const float*)d_in[14];
    const float* gw1    = (const float*)d_in[15];
    const float* bw1_bn = (const float*)d_in[16];
    const float* Ww1    = (const float*)d_in[17];
    const float* bw1    = (const float*)d_in[18];
    const float* gw2    = (const float*)d_in[19];
    const float* bw2_bn = (const float*)d_in[20];
    const float* Ww2    = (const float*)d_in[21];
    const float* bw2    = (const float*)d_in[22];
    float* ws  = (float*)d_ws;
    float* out = (float*)d_out;
    (void)in_sizes; (void)n_in; (void)out_size; (void)ws_size;

    hipMemsetAsync((char*)d_ws + (size_t)ST_OFF * 4, 0, 150 * sizeof(float), stream);

    k1_proj_bn1<<<512, 256, 0, stream>>>(p, x, idx, Wq, bq, Wk, bk, Wv, bv, Wp1, bp1, ws);
    k2_bn2<<<128, 256, 0, stream>>>(idx, gp, bp_bn, Wp2, bp2, ws);
    k2b_bn3<<<128, 256, 0, stream>>>(idx, gp, bp_bn, Wp2, bp2,
                                     gw1, bw1_bn, Ww1, bw1, ws);
    k34_fused<<<1024, 256, 0, stream>>>(idx, gp, bp_bn, Wp2, bp2,
                                        gw1, bw1_bn, Ww1, bw1,
                                        gw2, bw2_bn, Ww2, bw2, ws, out);
}